// Round 1
// baseline (1048.584 us; speedup 1.0000x reference)
//
#include <hip/hip_runtime.h>
#include <cstdint>
#include <cstddef>

#define NSEQ 1024
#define BATCH 8
#define CMODEL 512
#define NHEAD 8
#define HDIM 64

#define FLTMAX 3.402823466e+38f

// ---------------------------------------------------------------------------
// Fill kernel (u32 grid-stride)
// ---------------------------------------------------------------------------
__global__ void fill_u32(unsigned int* __restrict__ p, unsigned int n, unsigned int v) {
    unsigned int i = blockIdx.x * blockDim.x + threadIdx.x;
    unsigned int stride = gridDim.x * blockDim.x;
    for (; i < n; i += stride) p[i] = v;
}

// ---------------------------------------------------------------------------
// K1: per (b, s) find 5 nearest targets; zero their mask bytes.
// mask[b][t][s] byte: 1 = masked, 0 = attend.
// ---------------------------------------------------------------------------
__global__ __launch_bounds__(256) void topk_mask(const float* __restrict__ srcp,
                                                 const float* __restrict__ tgtp,
                                                 unsigned char* __restrict__ mask) {
    const int s = blockIdx.x;
    const int b = blockIdx.y;
    const int tid = threadIdx.x;

    __shared__ float dv[NSEQ];
    __shared__ float rv[256];
    __shared__ int   ri[256];

    const float sx = srcp[((size_t)s * BATCH + b) * 3 + 0];
    const float sy = srcp[((size_t)s * BATCH + b) * 3 + 1];
    const float sz = srcp[((size_t)s * BATCH + b) * 3 + 2];

    #pragma unroll
    for (int i = 0; i < 4; ++i) {
        int t = tid + i * 256;
        float dx = tgtp[((size_t)t * BATCH + b) * 3 + 0] - sx;
        float dy = tgtp[((size_t)t * BATCH + b) * 3 + 1] - sy;
        float dz = tgtp[((size_t)t * BATCH + b) * 3 + 2] - sz;
        dv[t] = dx * dx + dy * dy + dz * dz;
    }
    __syncthreads();

    for (int k = 0; k < 5; ++k) {
        float bvv = FLTMAX;
        int   bii = 0x7fffffff;
        #pragma unroll
        for (int i = 0; i < 4; ++i) {
            int t = tid + i * 256;
            float v = dv[t];
            if (v < bvv || (v == bvv && t < bii)) { bvv = v; bii = t; }
        }
        rv[tid] = bvv; ri[tid] = bii;
        __syncthreads();
        for (int off = 128; off > 0; off >>= 1) {
            if (tid < off) {
                float v2 = rv[tid + off]; int i2 = ri[tid + off];
                if (v2 < rv[tid] || (v2 == rv[tid] && i2 < ri[tid])) {
                    rv[tid] = v2; ri[tid] = i2;
                }
            }
            __syncthreads();
        }
        if (tid == 0) {
            int tbest = ri[0];
            mask[((size_t)b * NSEQ + tbest) * NSEQ + s] = 0;
            dv[tbest] = FLTMAX;
        }
        __syncthreads();
    }
}

// ---------------------------------------------------------------------------
// K2: GEMM out = (A @ W^T + bias) * scale
// A: (8192, 512) row-major.  W: (512, 512) row-major, indexed W[n][k].
// mode 0: write to (b, h, t, d) layout  [for q/k/v staging]
// mode 1: write to flat (r, c) = out region (N,B,C)
// 64x64 tile, 16 K-step, 4x4 per thread.
// ---------------------------------------------------------------------------
__global__ __launch_bounds__(256) void gemm_xwT(const float* __restrict__ A,
                                                const float* __restrict__ W,
                                                const float* __restrict__ bias,
                                                float* __restrict__ out,
                                                float scale, int mode) {
    __shared__ float As[64][17];
    __shared__ float Bs[64][17];
    const int tid = threadIdx.x;
    const int tx = tid & 15, ty = tid >> 4;
    const int m0 = blockIdx.x * 64, n0 = blockIdx.y * 64;

    float acc[4][4] = {};

    const int lrow = tid >> 2;        // 0..63
    const int lc4  = (tid & 3) * 4;   // 0,4,8,12

    for (int k0 = 0; k0 < CMODEL; k0 += 16) {
        const float4 va = *(const float4*)(A + (size_t)(m0 + lrow) * CMODEL + k0 + lc4);
        const float4 vb = *(const float4*)(W + (size_t)(n0 + lrow) * CMODEL + k0 + lc4);
        As[lrow][lc4 + 0] = va.x; As[lrow][lc4 + 1] = va.y;
        As[lrow][lc4 + 2] = va.z; As[lrow][lc4 + 3] = va.w;
        Bs[lrow][lc4 + 0] = vb.x; Bs[lrow][lc4 + 1] = vb.y;
        Bs[lrow][lc4 + 2] = vb.z; Bs[lrow][lc4 + 3] = vb.w;
        __syncthreads();
        #pragma unroll
        for (int kk = 0; kk < 16; ++kk) {
            float a[4], bb[4];
            #pragma unroll
            for (int i = 0; i < 4; ++i) a[i] = As[ty * 4 + i][kk];
            #pragma unroll
            for (int j = 0; j < 4; ++j) bb[j] = Bs[tx * 4 + j][kk];
            #pragma unroll
            for (int i = 0; i < 4; ++i)
                #pragma unroll
                for (int j = 0; j < 4; ++j)
                    acc[i][j] += a[i] * bb[j];
        }
        __syncthreads();
    }

    #pragma unroll
    for (int i = 0; i < 4; ++i) {
        const int r = m0 + ty * 4 + i;
        #pragma unroll
        for (int j = 0; j < 4; ++j) {
            const int c = n0 + tx * 4 + j;
            const float v = (acc[i][j] + bias[c]) * scale;
            if (mode == 0) {
                const int t = r >> 3, b = r & 7;
                const int h = c >> 6, d = c & 63;
                out[(((size_t)(b * NHEAD + h)) * NSEQ + t) * HDIM + d] = v;
            } else {
                out[(size_t)r * CMODEL + c] = v;
            }
        }
    }
}

// ---------------------------------------------------------------------------
// 64x64 fp32 tile loader: global (rows contiguous 64 floats) -> LDS [64][65]
// ---------------------------------------------------------------------------
__device__ inline void load_tile64(const float* __restrict__ src, int row0,
                                   float (*S)[65], int tid) {
    const int r  = tid >> 4;         // 0..15
    const int c4 = (tid & 15) * 4;   // 0..60
    #pragma unroll
    for (int p = 0; p < 4; ++p) {
        const float4 v = *(const float4*)(src + (size_t)(row0 + r + p * 16) * HDIM + c4);
        S[r + p * 16][c4 + 0] = v.x; S[r + p * 16][c4 + 1] = v.y;
        S[r + p * 16][c4 + 2] = v.z; S[r + p * 16][c4 + 3] = v.w;
    }
}

// ---------------------------------------------------------------------------
// K3 (pass A): per (b,h,t): l = sum over unmasked s of exp(score), count.
// Stores inv_ws = 1/l  (or -1 sentinel if the whole row is masked).
// No max-subtraction needed: |score| < ~2 analytically.
// ---------------------------------------------------------------------------
__global__ __launch_bounds__(256) void attn_stats(const float* __restrict__ q_ws,
                                                  const float* __restrict__ k_ws,
                                                  const unsigned char* __restrict__ mask,
                                                  float* __restrict__ inv_ws) {
    __shared__ float Aq[64][65];
    __shared__ float Bk[64][65];
    __shared__ float red[64][17];

    const int tid = threadIdx.x;
    const int tx = tid & 15, ty = tid >> 4;
    const int t0 = blockIdx.x * 64;
    const int bh = blockIdx.y;      // b*8 + h
    const int b  = bh >> 3;

    const float* qbase = q_ws + (size_t)bh * NSEQ * HDIM;
    const float* kbase = k_ws + (size_t)bh * NSEQ * HDIM;

    load_tile64(qbase, t0, Aq, tid);

    float lsum[4] = {0.f, 0.f, 0.f, 0.f};
    float lcnt[4] = {0.f, 0.f, 0.f, 0.f};

    for (int s0 = 0; s0 < NSEQ; s0 += 64) {
        __syncthreads();
        load_tile64(kbase, s0, Bk, tid);
        __syncthreads();

        float acc[4][4] = {};
        #pragma unroll 16
        for (int kk = 0; kk < 64; ++kk) {
            float a[4], bb[4];
            #pragma unroll
            for (int i = 0; i < 4; ++i) a[i] = Aq[ty * 4 + i][kk];
            #pragma unroll
            for (int j = 0; j < 4; ++j) bb[j] = Bk[tx * 4 + j][kk];
            #pragma unroll
            for (int i = 0; i < 4; ++i)
                #pragma unroll
                for (int j = 0; j < 4; ++j)
                    acc[i][j] += a[i] * bb[j];
        }

        #pragma unroll
        for (int i = 0; i < 4; ++i) {
            const int t = t0 + ty * 4 + i;
            const unsigned char* mrow = mask + ((size_t)b * NSEQ + t) * NSEQ + s0 + tx * 4;
            #pragma unroll
            for (int j = 0; j < 4; ++j) {
                if (!mrow[j]) { lsum[i] += __expf(acc[i][j]); lcnt[i] += 1.f; }
            }
        }
    }

    __syncthreads();
    #pragma unroll
    for (int i = 0; i < 4; ++i) red[ty * 4 + i][tx] = lsum[i];
    __syncthreads();
    float rowsum = 0.f;
    if (tid < 64) {
        #pragma unroll
        for (int x = 0; x < 16; ++x) rowsum += red[tid][x];
    }
    __syncthreads();
    #pragma unroll
    for (int i = 0; i < 4; ++i) red[ty * 4 + i][tx] = lcnt[i];
    __syncthreads();
    if (tid < 64) {
        float cnt = 0.f;
        #pragma unroll
        for (int x = 0; x < 16; ++x) cnt += red[tid][x];
        inv_ws[(size_t)bh * NSEQ + t0 + tid] = (cnt > 0.f) ? (1.f / rowsum) : -1.f;
    }
}

// ---------------------------------------------------------------------------
// K4 (pass B): recompute scores, p = exp(s)*inv (or uniform 1/N), accumulate
// attn_avg (atomics, skipping zeros) and ctx = P @ V.
// KV buffer shared between the K-tile and V-tile to stay under 64 KB LDS.
// ---------------------------------------------------------------------------
__global__ __launch_bounds__(256) void attn_pv(const float* __restrict__ q_ws,
                                               const float* __restrict__ k_ws,
                                               const float* __restrict__ v_ws,
                                               const unsigned char* __restrict__ mask,
                                               const float* __restrict__ inv_ws,
                                               float* __restrict__ ctx,
                                               float* __restrict__ attn_out) {
    __shared__ float Aq[64][65];
    __shared__ float KV[64][65];
    __shared__ float Pp[64][65];

    const int tid = threadIdx.x;
    const int tx = tid & 15, ty = tid >> 4;
    const int t0 = blockIdx.x * 64;
    const int bh = blockIdx.y;
    const int b  = bh >> 3, h = bh & 7;

    const float* qbase = q_ws + (size_t)bh * NSEQ * HDIM;
    const float* kbase = k_ws + (size_t)bh * NSEQ * HDIM;
    const float* vbase = v_ws + (size_t)bh * NSEQ * HDIM;

    load_tile64(qbase, t0, Aq, tid);

    float inv[4];
    #pragma unroll
    for (int i = 0; i < 4; ++i)
        inv[i] = inv_ws[(size_t)bh * NSEQ + t0 + ty * 4 + i];

    float ctxacc[4][4] = {};

    for (int s0 = 0; s0 < NSEQ; s0 += 64) {
        __syncthreads();                 // prev iter done reading KV/Pp
        load_tile64(kbase, s0, KV, tid);
        __syncthreads();

        float acc[4][4] = {};
        #pragma unroll 16
        for (int kk = 0; kk < 64; ++kk) {
            float a[4], bb[4];
            #pragma unroll
            for (int i = 0; i < 4; ++i) a[i] = Aq[ty * 4 + i][kk];
            #pragma unroll
            for (int j = 0; j < 4; ++j) bb[j] = KV[tx * 4 + j][kk];
            #pragma unroll
            for (int i = 0; i < 4; ++i)
                #pragma unroll
                for (int j = 0; j < 4; ++j)
                    acc[i][j] += a[i] * bb[j];
        }
        __syncthreads();                 // everyone done reading KV as K
        load_tile64(vbase, s0, KV, tid); // overwrite with V tile

        #pragma unroll
        for (int i = 0; i < 4; ++i) {
            const int t = t0 + ty * 4 + i;
            const unsigned char* mrow = mask + ((size_t)b * NSEQ + t) * NSEQ + s0 + tx * 4;
            #pragma unroll
            for (int j = 0; j < 4; ++j) {
                const int s = s0 + tx * 4 + j;
                float p;
                if (inv[i] < 0.f) {
                    p = 1.f / (float)NSEQ;          // fully-masked row -> uniform
                } else {
                    p = mrow[j] ? 0.f : __expf(acc[i][j]) * inv[i];
                }
                if (p != 0.f)
                    atomicAdd(&attn_out[((size_t)b * NSEQ + t) * NSEQ + s], p * 0.125f);
                Pp[ty * 4 + i][tx * 4 + j] = p;
            }
        }
        __syncthreads();                 // Pp + V tile ready

        #pragma unroll 16
        for (int kk = 0; kk < 64; ++kk) {
            float pr[4], vv[4];
            #pragma unroll
            for (int i = 0; i < 4; ++i) pr[i] = Pp[ty * 4 + i][kk];
            #pragma unroll
            for (int j = 0; j < 4; ++j) vv[j] = KV[kk][tx * 4 + j];
            #pragma unroll
            for (int i = 0; i < 4; ++i)
                #pragma unroll
                for (int j = 0; j < 4; ++j)
                    ctxacc[i][j] += pr[i] * vv[j];
        }
    }

    #pragma unroll
    for (int i = 0; i < 4; ++i) {
        const int t = t0 + ty * 4 + i;
        #pragma unroll
        for (int j = 0; j < 4; ++j) {
            const int d = tx * 4 + j;
            ctx[((size_t)t * BATCH + b) * CMODEL + h * HDIM + d] = ctxacc[i][j];
        }
    }
}

// ---------------------------------------------------------------------------
extern "C" void kernel_launch(void* const* d_in, const int* in_sizes, int n_in,
                              void* d_out, int out_size, void* d_ws, size_t ws_size,
                              hipStream_t stream) {
    (void)in_sizes; (void)n_in; (void)out_size; (void)ws_size;

    const float* query = (const float*)d_in[0];
    const float* key_t = (const float*)d_in[1];
    const float* value = (const float*)d_in[2];
    const float* srcp  = (const float*)d_in[3];
    const float* tgtp  = (const float*)d_in[4];
    const float* Wq    = (const float*)d_in[5];
    const float* Wk    = (const float*)d_in[6];
    const float* Wv    = (const float*)d_in[7];
    const float* bq    = (const float*)d_in[8];
    const float* bk    = (const float*)d_in[9];
    const float* bv    = (const float*)d_in[10];
    const float* Wo    = (const float*)d_in[11];
    const float* bo    = (const float*)d_in[12];

    float* out      = (float*)d_out;                          // (N,B,C) = 4,194,304 floats
    float* attn_out = out + (size_t)NSEQ * BATCH * CMODEL;    // (B,N,N) = 8,388,608 floats

    const size_t NBHD = (size_t)BATCH * NHEAD * NSEQ * HDIM;  // 4,194,304
    float* q_ws   = (float*)d_ws;
    float* k_ws   = q_ws + NBHD;
    float* v_ws   = k_ws + NBHD;
    float* ctx_ws = v_ws + NBHD;
    float* inv_ws = ctx_ws + NBHD;                            // 65,536 floats
    unsigned char* mask = (unsigned char*)(inv_ws + (size_t)BATCH * NHEAD * NSEQ);

    const unsigned int mask_words = (unsigned int)((size_t)BATCH * NSEQ * NSEQ / 4);
    const unsigned int attn_words = (unsigned int)((size_t)BATCH * NSEQ * NSEQ);

    fill_u32<<<1024, 256, 0, stream>>>((unsigned int*)mask, mask_words, 0x01010101u);
    fill_u32<<<1024, 256, 0, stream>>>((unsigned int*)attn_out, attn_words, 0u);

    topk_mask<<<dim3(NSEQ, BATCH), 256, 0, stream>>>(srcp, tgtp, mask);

    // projections: M=8192 rows (t,b); grid (M/64, C/64)
    gemm_xwT<<<dim3(128, 8), 256, 0, stream>>>(query, Wq, bq, q_ws, 0.125f, 0);
    gemm_xwT<<<dim3(128, 8), 256, 0, stream>>>(key_t, Wk, bk, k_ws, 1.0f, 0);
    gemm_xwT<<<dim3(128, 8), 256, 0, stream>>>(value, Wv, bv, v_ws, 1.0f, 0);

    attn_stats<<<dim3(16, 64), 256, 0, stream>>>(q_ws, k_ws, mask, inv_ws);
    attn_pv<<<dim3(16, 64), 256, 0, stream>>>(q_ws, k_ws, v_ws, mask, inv_ws, ctx_ws, attn_out);

    // output projection -> d_out (N,B,C) flat
    gemm_xwT<<<dim3(128, 8), 256, 0, stream>>>(ctx_ws, Wo, bo, out, 1.0f, 1);
}

// Round 2
// 462.032 us; speedup vs baseline: 2.2695x; 2.2695x over previous
//
#include <hip/hip_runtime.h>
#include <cstdint>
#include <cstddef>

#define NSEQ 1024
#define BATCH 8
#define CMODEL 512
#define NHEAD 8
#define HDIM 64
#define CAP 64

#define FLTMAX 3.402823466e+38f

// ---------------------------------------------------------------------------
// Fill kernel (u32 grid-stride)
// ---------------------------------------------------------------------------
__global__ void fill_u32(unsigned int* __restrict__ p, unsigned int n, unsigned int v) {
    unsigned int i = blockIdx.x * blockDim.x + threadIdx.x;
    unsigned int stride = gridDim.x * blockDim.x;
    for (; i < n; i += stride) p[i] = v;
}

// ---------------------------------------------------------------------------
// K1: per (b, s) find 5 nearest targets; append s to each target's row list.
// row_cnt[b*N + t], row_list[(b*N + t)*CAP + pos] = s
// ---------------------------------------------------------------------------
__global__ __launch_bounds__(256) void topk_scatter(const float* __restrict__ srcp,
                                                    const float* __restrict__ tgtp,
                                                    int* __restrict__ row_cnt,
                                                    int* __restrict__ row_list) {
    const int s = blockIdx.x;
    const int b = blockIdx.y;
    const int tid = threadIdx.x;

    __shared__ float dv[NSEQ];
    __shared__ float rv[256];
    __shared__ int   ri[256];

    const float sx = srcp[((size_t)s * BATCH + b) * 3 + 0];
    const float sy = srcp[((size_t)s * BATCH + b) * 3 + 1];
    const float sz = srcp[((size_t)s * BATCH + b) * 3 + 2];

    #pragma unroll
    for (int i = 0; i < 4; ++i) {
        int t = tid + i * 256;
        float dx = tgtp[((size_t)t * BATCH + b) * 3 + 0] - sx;
        float dy = tgtp[((size_t)t * BATCH + b) * 3 + 1] - sy;
        float dz = tgtp[((size_t)t * BATCH + b) * 3 + 2] - sz;
        dv[t] = dx * dx + dy * dy + dz * dz;
    }
    __syncthreads();

    for (int k = 0; k < 5; ++k) {
        float bvv = FLTMAX;
        int   bii = 0x7fffffff;
        #pragma unroll
        for (int i = 0; i < 4; ++i) {
            int t = tid + i * 256;
            float v = dv[t];
            if (v < bvv || (v == bvv && t < bii)) { bvv = v; bii = t; }
        }
        rv[tid] = bvv; ri[tid] = bii;
        __syncthreads();
        for (int off = 128; off > 0; off >>= 1) {
            if (tid < off) {
                float v2 = rv[tid + off]; int i2 = ri[tid + off];
                if (v2 < rv[tid] || (v2 == rv[tid] && i2 < ri[tid])) {
                    rv[tid] = v2; ri[tid] = i2;
                }
            }
            __syncthreads();
        }
        if (tid == 0) {
            int tbest = ri[0];
            int pos = atomicAdd(&row_cnt[b * NSEQ + tbest], 1);
            if (pos < CAP) row_list[((size_t)b * NSEQ + tbest) * CAP + pos] = s;
            dv[tbest] = FLTMAX;
        }
        __syncthreads();
    }
}

// ---------------------------------------------------------------------------
// K2: GEMM out = (A @ W^T + bias) * scale
// A: (8192, 512) row-major, row r = t*8 + b.  W: (512, 512) row-major W[n][k].
// mode 0: write to (b, t, c) layout  [q/k/v staging for sparse attention]
// mode 1: write flat (r, c)          [final output (N,B,C)]
// ---------------------------------------------------------------------------
__global__ __launch_bounds__(256) void gemm_xwT(const float* __restrict__ A,
                                                const float* __restrict__ W,
                                                const float* __restrict__ bias,
                                                float* __restrict__ out,
                                                float scale, int mode) {
    __shared__ float As[64][17];
    __shared__ float Bs[64][17];
    const int tid = threadIdx.x;
    const int tx = tid & 15, ty = tid >> 4;
    const int m0 = blockIdx.x * 64, n0 = blockIdx.y * 64;

    float acc[4][4] = {};

    const int lrow = tid >> 2;        // 0..63
    const int lc4  = (tid & 3) * 4;   // 0,4,8,12

    for (int k0 = 0; k0 < CMODEL; k0 += 16) {
        const float4 va = *(const float4*)(A + (size_t)(m0 + lrow) * CMODEL + k0 + lc4);
        const float4 vb = *(const float4*)(W + (size_t)(n0 + lrow) * CMODEL + k0 + lc4);
        As[lrow][lc4 + 0] = va.x; As[lrow][lc4 + 1] = va.y;
        As[lrow][lc4 + 2] = va.z; As[lrow][lc4 + 3] = va.w;
        Bs[lrow][lc4 + 0] = vb.x; Bs[lrow][lc4 + 1] = vb.y;
        Bs[lrow][lc4 + 2] = vb.z; Bs[lrow][lc4 + 3] = vb.w;
        __syncthreads();
        #pragma unroll
        for (int kk = 0; kk < 16; ++kk) {
            float a[4], bb[4];
            #pragma unroll
            for (int i = 0; i < 4; ++i) a[i] = As[ty * 4 + i][kk];
            #pragma unroll
            for (int j = 0; j < 4; ++j) bb[j] = Bs[tx * 4 + j][kk];
            #pragma unroll
            for (int i = 0; i < 4; ++i)
                #pragma unroll
                for (int j = 0; j < 4; ++j)
                    acc[i][j] += a[i] * bb[j];
        }
        __syncthreads();
    }

    #pragma unroll
    for (int i = 0; i < 4; ++i) {
        const int r = m0 + ty * 4 + i;
        #pragma unroll
        for (int j = 0; j < 4; ++j) {
            const int c = n0 + tx * 4 + j;
            const float v = (acc[i][j] + bias[c]) * scale;
            if (mode == 0) {
                const int t = r >> 3, b = r & 7;
                out[((size_t)b * NSEQ + t) * CMODEL + c] = v;
            } else {
                out[(size_t)r * CMODEL + c] = v;
            }
        }
    }
}

// ---------------------------------------------------------------------------
// K3: v_mean partials — vm[b][c] += (1/1024) * sum over 64 t-rows.
// grid (BATCH, 16); vm must be zeroed first.
// ---------------------------------------------------------------------------
__global__ __launch_bounds__(512) void v_mean_k(const float* __restrict__ v,
                                                float* __restrict__ vm) {
    const int b = blockIdx.x;
    const int chunk = blockIdx.y;          // 0..15 -> 64 rows each
    const int c = threadIdx.x;             // 0..511
    float s = 0.f;
    const int t0 = chunk * 64;
    for (int t = 0; t < 64; ++t)
        s += v[((size_t)b * NSEQ + t0 + t) * CMODEL + c];
    atomicAdd(&vm[b * CMODEL + c], s * (1.f / (float)NSEQ));
}

// ---------------------------------------------------------------------------
// K4: sparse attention. One block per (t, b). 256 threads = 4 waves.
// q/k/v in (b, t, c) layout, c = h*64 + d.
// ---------------------------------------------------------------------------
__global__ __launch_bounds__(256) void sparse_attn(const float* __restrict__ q_ws,
                                                   const float* __restrict__ k_ws,
                                                   const float* __restrict__ v_ws,
                                                   const int* __restrict__ row_cnt,
                                                   const int* __restrict__ row_list,
                                                   const float* __restrict__ vm,
                                                   float* __restrict__ ctx,
                                                   float* __restrict__ attn_out) {
    const int t = blockIdx.x;
    const int b = blockIdx.y;
    const int tid = threadIdx.x;

    int cnt = row_cnt[b * NSEQ + t];
    if (cnt > CAP) cnt = CAP;

    if (cnt == 0) {
        // fully-masked row: uniform attention, ctx = mean(v)
        const float u = 1.f / (float)NSEQ;
        for (int s = tid; s < NSEQ; s += 256)
            attn_out[((size_t)b * NSEQ + t) * NSEQ + s] = u;
        for (int c = tid; c < CMODEL; c += 256)
            ctx[((size_t)t * BATCH + b) * CMODEL + c] = vm[b * CMODEL + c];
        return;
    }

    __shared__ float qs[CMODEL];
    __shared__ float esc[CAP][8];
    __shared__ float denom[8];
    __shared__ int   slist[CAP];

    if (tid < 8) denom[tid] = 0.f;
    if (tid < cnt) slist[tid] = row_list[((size_t)b * NSEQ + t) * CAP + tid];
    {
        const float2 qv = *(const float2*)(q_ws + ((size_t)b * NSEQ + t) * CMODEL + tid * 2);
        qs[tid * 2] = qv.x; qs[tid * 2 + 1] = qv.y;
    }
    __syncthreads();

    // Phase 1: scores. wave w handles entries i = w, w+4, ...
    const int wid = tid >> 6, lane = tid & 63;
    for (int i = wid; i < cnt; i += 4) {
        const int s = slist[i];
        const float* krow = k_ws + ((size_t)b * NSEQ + s) * CMODEL + lane * 8;
        const float* qrow = qs + lane * 8;
        float part = 0.f;
        #pragma unroll
        for (int j = 0; j < 8; ++j) part += qrow[j] * krow[j];
        part += __shfl_xor(part, 1);
        part += __shfl_xor(part, 2);
        part += __shfl_xor(part, 4);
        if ((lane & 7) == 0) {
            const int h = lane >> 3;
            const float e = __expf(part);
            esc[i][h] = e;
            atomicAdd(&denom[h], e);
        }
    }
    __syncthreads();

    // normalize: p = esc/denom
    for (int x = tid; x < cnt * 8; x += 256)
        esc[x >> 3][x & 7] /= denom[x & 7];
    __syncthreads();

    // attn_avg stores (one per nonzero; unique (b,t,s) -> plain store)
    for (int i = tid; i < cnt; i += 256) {
        float pm = 0.f;
        #pragma unroll
        for (int h = 0; h < 8; ++h) pm += esc[i][h];
        attn_out[((size_t)b * NSEQ + t) * NSEQ + slist[i]] = pm * 0.125f;
    }

    // ctx = P @ V (sparse): each thread owns 2 consecutive c's
    const int c0 = tid * 2;
    const int h0 = c0 >> 6;
    float acc0 = 0.f, acc1 = 0.f;
    for (int i = 0; i < cnt; ++i) {
        const int s = slist[i];
        const float p = esc[i][h0];
        const float2 vv = *(const float2*)(v_ws + ((size_t)b * NSEQ + s) * CMODEL + c0);
        acc0 += p * vv.x; acc1 += p * vv.y;
    }
    float* crow = ctx + ((size_t)t * BATCH + b) * CMODEL;
    crow[c0] = acc0; crow[c0 + 1] = acc1;
}

// ---------------------------------------------------------------------------
extern "C" void kernel_launch(void* const* d_in, const int* in_sizes, int n_in,
                              void* d_out, int out_size, void* d_ws, size_t ws_size,
                              hipStream_t stream) {
    (void)in_sizes; (void)n_in; (void)out_size; (void)ws_size;

    const float* query = (const float*)d_in[0];
    const float* key_t = (const float*)d_in[1];
    const float* value = (const float*)d_in[2];
    const float* srcp  = (const float*)d_in[3];
    const float* tgtp  = (const float*)d_in[4];
    const float* Wq    = (const float*)d_in[5];
    const float* Wk    = (const float*)d_in[6];
    const float* Wv    = (const float*)d_in[7];
    const float* bq    = (const float*)d_in[8];
    const float* bk    = (const float*)d_in[9];
    const float* bv    = (const float*)d_in[10];
    const float* Wo    = (const float*)d_in[11];
    const float* bo    = (const float*)d_in[12];

    float* out      = (float*)d_out;                          // (N,B,C)
    float* attn_out = out + (size_t)NSEQ * BATCH * CMODEL;    // (B,N,N)

    const size_t NBC = (size_t)BATCH * NSEQ * CMODEL;         // 4,194,304
    float* q_ws   = (float*)d_ws;
    float* k_ws   = q_ws + NBC;
    float* v_ws   = k_ws + NBC;
    float* ctx_ws = v_ws + NBC;
    int*   row_cnt  = (int*)(ctx_ws + NBC);                   // 8192 ints
    float* vm       = (float*)(row_cnt + BATCH * NSEQ);       // 4096 floats
    int*   row_list = (int*)(vm + BATCH * CMODEL);            // 8192*CAP ints

    const unsigned int attn_words = (unsigned int)((size_t)BATCH * NSEQ * NSEQ);

    fill_u32<<<1024, 256, 0, stream>>>((unsigned int*)attn_out, attn_words, 0u);
    fill_u32<<<48, 256, 0, stream>>>((unsigned int*)row_cnt,
                                     (unsigned int)(BATCH * NSEQ + BATCH * CMODEL), 0u);

    topk_scatter<<<dim3(NSEQ, BATCH), 256, 0, stream>>>(srcp, tgtp, row_cnt, row_list);

    gemm_xwT<<<dim3(128, 8), 256, 0, stream>>>(query, Wq, bq, q_ws, 0.125f, 0);
    gemm_xwT<<<dim3(128, 8), 256, 0, stream>>>(key_t, Wk, bk, k_ws, 1.0f, 0);
    gemm_xwT<<<dim3(128, 8), 256, 0, stream>>>(value, Wv, bv, v_ws, 1.0f, 0);

    v_mean_k<<<dim3(BATCH, 16), 512, 0, stream>>>(v_ws, vm);

    sparse_attn<<<dim3(NSEQ, BATCH), 256, 0, stream>>>(q_ws, k_ws, v_ws, row_cnt,
                                                       row_list, vm, ctx_ws, attn_out);

    gemm_xwT<<<dim3(128, 8), 256, 0, stream>>>(ctx_ws, Wo, bo, out, 1.0f, 1);
}

// Round 3
// 158.049 us; speedup vs baseline: 6.6345x; 2.9233x over previous
//
#include <hip/hip_runtime.h>
#include <cstdint>
#include <cstddef>

#define NSEQ 1024
#define BATCH 8
#define CMODEL 512
#define NHEAD 8
#define HDIM 64
#define CAP 64
#define FLTMAX 3.402823466e+38f

typedef short bf16x8 __attribute__((ext_vector_type(8)));
typedef float f32x4 __attribute__((ext_vector_type(4)));
typedef unsigned short ushort8v __attribute__((ext_vector_type(8)));
typedef unsigned short ushort2v __attribute__((ext_vector_type(2)));

__device__ inline unsigned short f2bf(float f) {
    unsigned int u = __builtin_bit_cast(unsigned int, f);
    u += 0x7fffu + ((u >> 16) & 1u);
    return (unsigned short)(u >> 16);
}

// ---------------------------------------------------------------------------
__global__ void fill_u32(unsigned int* __restrict__ p, unsigned int n, unsigned int v) {
    unsigned int i = blockIdx.x * blockDim.x + threadIdx.x;
    unsigned int stride = gridDim.x * blockDim.x;
    for (; i < n; i += stride) p[i] = v;
}

// ---------------------------------------------------------------------------
// K1: per (b, s) find 5 nearest targets; append s to each target's row list.
// ---------------------------------------------------------------------------
__global__ __launch_bounds__(256) void topk_scatter(const float* __restrict__ srcp,
                                                    const float* __restrict__ tgtp,
                                                    int* __restrict__ row_cnt,
                                                    int* __restrict__ row_list) {
    const int s = blockIdx.x;
    const int b = blockIdx.y;
    const int tid = threadIdx.x;

    __shared__ float dv[NSEQ];
    __shared__ float rv[256];
    __shared__ int   ri[256];

    const float sx = srcp[((size_t)s * BATCH + b) * 3 + 0];
    const float sy = srcp[((size_t)s * BATCH + b) * 3 + 1];
    const float sz = srcp[((size_t)s * BATCH + b) * 3 + 2];

    #pragma unroll
    for (int i = 0; i < 4; ++i) {
        int t = tid + i * 256;
        float dx = tgtp[((size_t)t * BATCH + b) * 3 + 0] - sx;
        float dy = tgtp[((size_t)t * BATCH + b) * 3 + 1] - sy;
        float dz = tgtp[((size_t)t * BATCH + b) * 3 + 2] - sz;
        dv[t] = dx * dx + dy * dy + dz * dz;
    }
    __syncthreads();

    for (int k = 0; k < 5; ++k) {
        float bvv = FLTMAX;
        int   bii = 0x7fffffff;
        #pragma unroll
        for (int i = 0; i < 4; ++i) {
            int t = tid + i * 256;
            float v = dv[t];
            if (v < bvv || (v == bvv && t < bii)) { bvv = v; bii = t; }
        }
        rv[tid] = bvv; ri[tid] = bii;
        __syncthreads();
        for (int off = 128; off > 0; off >>= 1) {
            if (tid < off) {
                float v2 = rv[tid + off]; int i2 = ri[tid + off];
                if (v2 < rv[tid] || (v2 == rv[tid] && i2 < ri[tid])) {
                    rv[tid] = v2; ri[tid] = i2;
                }
            }
            __syncthreads();
        }
        if (tid == 0) {
            int tbest = ri[0];
            int pos = atomicAdd(&row_cnt[b * NSEQ + tbest], 1);
            if (pos < CAP) row_list[((size_t)b * NSEQ + tbest) * CAP + pos] = s;
            dv[tbest] = FLTMAX;
        }
        __syncthreads();
    }
}

// ---------------------------------------------------------------------------
// Convert the 4 weight matrices fp32 -> bf16 (512x512 each).
// ---------------------------------------------------------------------------
__global__ __launch_bounds__(256) void convert_w(const float* __restrict__ w0,
                                                 const float* __restrict__ w1,
                                                 const float* __restrict__ w2,
                                                 const float* __restrict__ w3,
                                                 unsigned short* __restrict__ o0,
                                                 unsigned short* __restrict__ o1,
                                                 unsigned short* __restrict__ o2,
                                                 unsigned short* __restrict__ o3) {
    const int idx = blockIdx.x * 256 + threadIdx.x;        // 0..131071
    const int rgn = idx >> 15;                              // 32768 chunks/region
    const int c   = idx & 32767;
    const float* src = rgn == 0 ? w0 : rgn == 1 ? w1 : rgn == 2 ? w2 : w3;
    unsigned short* dst = rgn == 0 ? o0 : rgn == 1 ? o1 : rgn == 2 ? o2 : o3;
    const float4 v0 = *(const float4*)(src + (size_t)c * 8);
    const float4 v1 = *(const float4*)(src + (size_t)c * 8 + 4);
    ushort8v u;
    u[0] = f2bf(v0.x); u[1] = f2bf(v0.y); u[2] = f2bf(v0.z); u[3] = f2bf(v0.w);
    u[4] = f2bf(v1.x); u[5] = f2bf(v1.y); u[6] = f2bf(v1.z); u[7] = f2bf(v1.w);
    *(ushort8v*)(dst + (size_t)c * 8) = u;
}

// ---------------------------------------------------------------------------
// K2: MFMA GEMM  out = (A @ W^T + bias) * scale
// A: (8192, 512) rows r = t*8+b.  AMODE 0: fp32 (convert during staging),
// AMODE 1: bf16 (global_load_lds).  W: bf16 (512,512) row-major W[n][k].
// OMODE 0: write (b,t,c).  OMODE 1: write flat (r,c).
// Tile 128x64, BK=32, 4 waves 2x2, wave = 64x32 = 4x2 16x16 fragments.
// LDS: A [128][32] bf16 @0 (8KB), B [64][32] bf16 @8192 (4KB).
// XOR swizzle: chunk' = chunk ^ ((row>>1)&3) (16B chunks within 64B row).
// ---------------------------------------------------------------------------
template<int AMODE, int OMODE>
__global__ __launch_bounds__(256, 2) void gemm_mfma(const void* __restrict__ Ap,
                                                    const unsigned short* __restrict__ Wbf,
                                                    const float* __restrict__ bias,
                                                    float* __restrict__ out,
                                                    float scale) {
    __shared__ __align__(16) char smem[12288];
    const int tid = threadIdx.x;
    const int l = tid & 63, w = tid >> 6;
    const int m0 = blockIdx.x * 128, n0 = blockIdx.y * 64;
    const int wr = (w >> 1) * 64, wc = (w & 1) * 32;
    const int lr = l & 15, g = l >> 4;

    f32x4 acc[4][2] = {};

    // B staging addresses (global_load_lds, pre-swizzled source)
    const int rowB = w * 16 + (l >> 2);
    const int gkB  = (l & 3) ^ ((rowB >> 1) & 3);
    const unsigned short* bsrc = Wbf + (size_t)(n0 + rowB) * CMODEL + gkB * 8;
    char* bdst = smem + 8192 + w * 1024;        // wave-uniform

    // A staging addresses
    const float* asrc0 = nullptr; const float* asrc1 = nullptr;
    char* adst0 = nullptr; char* adst1 = nullptr;
    const unsigned short* asrcW0 = nullptr; const unsigned short* asrcW1 = nullptr;
    char* adstW0 = nullptr; char* adstW1 = nullptr;
    if constexpr (AMODE == 0) {
        const int rowA = tid >> 2;               // 0..63
        const int slA  = tid & 3;
        const int gkA  = slA ^ ((rowA >> 1) & 3);   // same for rowA+64
        asrc0 = (const float*)Ap + (size_t)(m0 + rowA) * CMODEL + gkA * 8;
        asrc1 = asrc0 + (size_t)64 * CMODEL;
        adst0 = smem + rowA * 64 + slA * 16;
        adst1 = adst0 + 64 * 64;
    } else {
        const unsigned short* Abf = (const unsigned short*)Ap;
        const int rA0 = w * 16 + (l >> 2);           // issue q = w
        const int gk0 = (l & 3) ^ ((rA0 >> 1) & 3);  // same for rA0+64
        asrcW0 = Abf + (size_t)(m0 + rA0) * CMODEL + gk0 * 8;
        asrcW1 = asrcW0 + (size_t)64 * CMODEL;
        adstW0 = smem + w * 1024;                    // wave-uniform
        adstW1 = adstW0 + 4096;
    }

    for (int k0 = 0; k0 < CMODEL; k0 += 32) {
        float4 a00, a01, a10, a11;
        if constexpr (AMODE == 0) {   // prefetch to regs before barrier (no LDS touch)
            a00 = *(const float4*)(asrc0 + k0);
            a01 = *(const float4*)(asrc0 + k0 + 4);
            a10 = *(const float4*)(asrc1 + k0);
            a11 = *(const float4*)(asrc1 + k0 + 4);
        }
        __syncthreads();   // previous compute done reading LDS

        __builtin_amdgcn_global_load_lds(
            (const __attribute__((address_space(1))) void*)(bsrc + k0),
            (__attribute__((address_space(3))) void*)bdst, 16, 0, 0);

        if constexpr (AMODE == 0) {
            ushort8v u0, u1;
            u0[0] = f2bf(a00.x); u0[1] = f2bf(a00.y); u0[2] = f2bf(a00.z); u0[3] = f2bf(a00.w);
            u0[4] = f2bf(a01.x); u0[5] = f2bf(a01.y); u0[6] = f2bf(a01.z); u0[7] = f2bf(a01.w);
            u1[0] = f2bf(a10.x); u1[1] = f2bf(a10.y); u1[2] = f2bf(a10.z); u1[3] = f2bf(a10.w);
            u1[4] = f2bf(a11.x); u1[5] = f2bf(a11.y); u1[6] = f2bf(a11.z); u1[7] = f2bf(a11.w);
            *(ushort8v*)adst0 = u0;
            *(ushort8v*)adst1 = u1;
        } else {
            __builtin_amdgcn_global_load_lds(
                (const __attribute__((address_space(1))) void*)(asrcW0 + k0),
                (__attribute__((address_space(3))) void*)adstW0, 16, 0, 0);
            __builtin_amdgcn_global_load_lds(
                (const __attribute__((address_space(1))) void*)(asrcW1 + k0),
                (__attribute__((address_space(3))) void*)adstW1, 16, 0, 0);
        }
        __syncthreads();   // staging complete (vmcnt+lgkm drained by barrier)

        bf16x8 af[4], bfr[2];
        #pragma unroll
        for (int i = 0; i < 4; ++i) {
            const int ra = wr + i * 16 + lr;
            af[i] = *(const bf16x8*)(smem + ra * 64 + ((g ^ ((ra >> 1) & 3)) << 4));
        }
        #pragma unroll
        for (int j = 0; j < 2; ++j) {
            const int rb = wc + j * 16 + lr;
            bfr[j] = *(const bf16x8*)(smem + 8192 + rb * 64 + ((g ^ ((rb >> 1) & 3)) << 4));
        }
        #pragma unroll
        for (int i = 0; i < 4; ++i)
            #pragma unroll
            for (int j = 0; j < 2; ++j)
                acc[i][j] = __builtin_amdgcn_mfma_f32_16x16x32_bf16(af[i], bfr[j], acc[i][j], 0, 0, 0);
    }

    #pragma unroll
    for (int i = 0; i < 4; ++i) {
        #pragma unroll
        for (int j = 0; j < 2; ++j) {
            const int col = n0 + wc + j * 16 + lr;
            const float bcol = bias[col];
            #pragma unroll
            for (int r = 0; r < 4; ++r) {
                const int row = m0 + wr + i * 16 + g * 4 + r;
                const float val = (acc[i][j][r] + bcol) * scale;
                if constexpr (OMODE == 0) {
                    const int t = row >> 3, b = row & 7;
                    out[((size_t)(b * NSEQ + t)) * CMODEL + col] = val;
                } else {
                    out[(size_t)row * CMODEL + col] = val;
                }
            }
        }
    }
}

// ---------------------------------------------------------------------------
// K3: v_mean partials — vm[b][c] += (1/1024) * sum over 64 t-rows.
// ---------------------------------------------------------------------------
__global__ __launch_bounds__(512) void v_mean_k(const float* __restrict__ v,
                                                float* __restrict__ vm) {
    const int b = blockIdx.x;
    const int chunk = blockIdx.y;
    const int c = threadIdx.x;
    float s = 0.f;
    const int t0 = chunk * 64;
    for (int t = 0; t < 64; ++t)
        s += v[((size_t)b * NSEQ + t0 + t) * CMODEL + c];
    atomicAdd(&vm[b * CMODEL + c], s * (1.f / (float)NSEQ));
}

// ---------------------------------------------------------------------------
// K4: sparse attention. One block per (t, b). ctx written as bf16.
// ---------------------------------------------------------------------------
__global__ __launch_bounds__(256) void sparse_attn(const float* __restrict__ q_ws,
                                                   const float* __restrict__ k_ws,
                                                   const float* __restrict__ v_ws,
                                                   const int* __restrict__ row_cnt,
                                                   const int* __restrict__ row_list,
                                                   const float* __restrict__ vm,
                                                   unsigned short* __restrict__ ctx,
                                                   float* __restrict__ attn_out) {
    const int t = blockIdx.x;
    const int b = blockIdx.y;
    const int tid = threadIdx.x;

    int cnt = row_cnt[b * NSEQ + t];
    if (cnt > CAP) cnt = CAP;

    if (cnt == 0) {
        const float u = 1.f / (float)NSEQ;
        for (int s = tid; s < NSEQ; s += 256)
            attn_out[((size_t)b * NSEQ + t) * NSEQ + s] = u;
        for (int c = tid; c < CMODEL; c += 256)
            ctx[((size_t)t * BATCH + b) * CMODEL + c] = f2bf(vm[b * CMODEL + c]);
        return;
    }

    __shared__ float qs[CMODEL];
    __shared__ float esc[CAP][8];
    __shared__ float denom[8];
    __shared__ int   slist[CAP];

    if (tid < 8) denom[tid] = 0.f;
    if (tid < cnt) slist[tid] = row_list[((size_t)b * NSEQ + t) * CAP + tid];
    {
        const float2 qv = *(const float2*)(q_ws + ((size_t)b * NSEQ + t) * CMODEL + tid * 2);
        qs[tid * 2] = qv.x; qs[tid * 2 + 1] = qv.y;
    }
    __syncthreads();

    const int wid = tid >> 6, lane = tid & 63;
    for (int i = wid; i < cnt; i += 4) {
        const int s = slist[i];
        const float* krow = k_ws + ((size_t)b * NSEQ + s) * CMODEL + lane * 8;
        const float* qrow = qs + lane * 8;
        float part = 0.f;
        #pragma unroll
        for (int j = 0; j < 8; ++j) part += qrow[j] * krow[j];
        part += __shfl_xor(part, 1);
        part += __shfl_xor(part, 2);
        part += __shfl_xor(part, 4);
        if ((lane & 7) == 0) {
            const int h = lane >> 3;
            const float e = __expf(part);
            esc[i][h] = e;
            atomicAdd(&denom[h], e);
        }
    }
    __syncthreads();

    for (int x = tid; x < cnt * 8; x += 256)
        esc[x >> 3][x & 7] /= denom[x & 7];
    __syncthreads();

    for (int i = tid; i < cnt; i += 256) {
        float pm = 0.f;
        #pragma unroll
        for (int h = 0; h < 8; ++h) pm += esc[i][h];
        attn_out[((size_t)b * NSEQ + t) * NSEQ + slist[i]] = pm * 0.125f;
    }

    const int c0 = tid * 2;
    const int h0 = c0 >> 6;
    float acc0 = 0.f, acc1 = 0.f;
    for (int i = 0; i < cnt; ++i) {
        const int s = slist[i];
        const float p = esc[i][h0];
        const float2 vv = *(const float2*)(v_ws + ((size_t)b * NSEQ + s) * CMODEL + c0);
        acc0 += p * vv.x; acc1 += p * vv.y;
    }
    unsigned short* crow = ctx + ((size_t)t * BATCH + b) * CMODEL;
    ushort2v cv; cv[0] = f2bf(acc0); cv[1] = f2bf(acc1);
    *(ushort2v*)(crow + c0) = cv;
}

// ---------------------------------------------------------------------------
extern "C" void kernel_launch(void* const* d_in, const int* in_sizes, int n_in,
                              void* d_out, int out_size, void* d_ws, size_t ws_size,
                              hipStream_t stream) {
    (void)in_sizes; (void)n_in; (void)out_size; (void)ws_size;

    const float* query = (const float*)d_in[0];
    const float* key_t = (const float*)d_in[1];
    const float* value = (const float*)d_in[2];
    const float* srcp  = (const float*)d_in[3];
    const float* tgtp  = (const float*)d_in[4];
    const float* Wq    = (const float*)d_in[5];
    const float* Wk    = (const float*)d_in[6];
    const float* Wv    = (const float*)d_in[7];
    const float* bq    = (const float*)d_in[8];
    const float* bk    = (const float*)d_in[9];
    const float* bv    = (const float*)d_in[10];
    const float* Wo    = (const float*)d_in[11];
    const float* bo    = (const float*)d_in[12];

    float* out      = (float*)d_out;                          // (N,B,C)
    float* attn_out = out + (size_t)NSEQ * BATCH * CMODEL;    // (B,N,N)

    const size_t NBC = (size_t)BATCH * NSEQ * CMODEL;         // 4,194,304
    const size_t WSZ = (size_t)CMODEL * CMODEL;               // 262,144
    float* q_ws = (float*)d_ws;
    float* k_ws = q_ws + NBC;
    float* v_ws = k_ws + NBC;
    unsigned short* ctxbf = (unsigned short*)(v_ws + NBC);
    unsigned short* wqbf  = ctxbf + NBC;
    unsigned short* wkbf  = wqbf + WSZ;
    unsigned short* wvbf  = wkbf + WSZ;
    unsigned short* wobf  = wvbf + WSZ;
    int*   row_cnt  = (int*)(wobf + WSZ);                     // 8192 ints
    float* vm       = (float*)(row_cnt + BATCH * NSEQ);       // 4096 floats (contiguous w/ row_cnt)
    int*   row_list = (int*)(vm + BATCH * CMODEL);            // 8192*CAP ints

    const unsigned int attn_words = (unsigned int)((size_t)BATCH * NSEQ * NSEQ);

    fill_u32<<<1024, 256, 0, stream>>>((unsigned int*)attn_out, attn_words, 0u);
    fill_u32<<<12, 256, 0, stream>>>((unsigned int*)row_cnt, 12288u, 0u);

    convert_w<<<512, 256, 0, stream>>>(Wq, Wk, Wv, Wo, wqbf, wkbf, wvbf, wobf);

    topk_scatter<<<dim3(NSEQ, BATCH), 256, 0, stream>>>(srcp, tgtp, row_cnt, row_list);

    gemm_mfma<0, 0><<<dim3(64, 8), 256, 0, stream>>>(query, wqbf, bq, q_ws, 0.125f);
    gemm_mfma<0, 0><<<dim3(64, 8), 256, 0, stream>>>(key_t, wkbf, bk, k_ws, 1.0f);
    gemm_mfma<0, 0><<<dim3(64, 8), 256, 0, stream>>>(value, wvbf, bv, v_ws, 1.0f);

    v_mean_k<<<dim3(BATCH, 16), 512, 0, stream>>>(v_ws, vm);

    sparse_attn<<<dim3(NSEQ, BATCH), 256, 0, stream>>>(q_ws, k_ws, v_ws, row_cnt,
                                                       row_list, vm, ctxbf, attn_out);

    gemm_mfma<1, 1><<<dim3(64, 8), 256, 0, stream>>>(ctxbf, wobf, bo, out, 1.0f);
}

// Round 4
// 101.523 us; speedup vs baseline: 10.3286x; 1.5568x over previous
//
#include <hip/hip_runtime.h>
#include <cstdint>
#include <cstddef>

#define NSEQ 1024
#define BATCH 8
#define CMODEL 512
#define NHEAD 8
#define HDIM 64
#define CAP 64
#define FLTMAX 3.402823466e+38f

typedef short bf16x8 __attribute__((ext_vector_type(8)));
typedef float f32x4 __attribute__((ext_vector_type(4)));
typedef unsigned short ushort8v __attribute__((ext_vector_type(8)));
typedef unsigned short ushort2v __attribute__((ext_vector_type(2)));

__device__ inline unsigned short f2bf(float f) {
    unsigned int u = __builtin_bit_cast(unsigned int, f);
    u += 0x7fffu + ((u >> 16) & 1u);
    return (unsigned short)(u >> 16);
}

// ---------------------------------------------------------------------------
// K0: convert 4 weight matrices fp32->bf16 (blocks 0..511) and zero
// row_cnt+vm (blocks 512..559).
// ---------------------------------------------------------------------------
__global__ __launch_bounds__(256) void convert_w(const float* __restrict__ w0,
                                                 const float* __restrict__ w1,
                                                 const float* __restrict__ w2,
                                                 const float* __restrict__ w3,
                                                 unsigned short* __restrict__ o0,
                                                 unsigned short* __restrict__ o1,
                                                 unsigned short* __restrict__ o2,
                                                 unsigned short* __restrict__ o3,
                                                 unsigned int* __restrict__ zp) {
    if (blockIdx.x >= 512) {
        const int zi = (blockIdx.x - 512) * 256 + threadIdx.x;   // < 12288
        zp[zi] = 0u;
        return;
    }
    const int idx = blockIdx.x * 256 + threadIdx.x;        // 0..131071
    const int rgn = idx >> 15;
    const int c   = idx & 32767;
    const float* src = rgn == 0 ? w0 : rgn == 1 ? w1 : rgn == 2 ? w2 : w3;
    unsigned short* dst = rgn == 0 ? o0 : rgn == 1 ? o1 : rgn == 2 ? o2 : o3;
    const float4 v0 = *(const float4*)(src + (size_t)c * 8);
    const float4 v1 = *(const float4*)(src + (size_t)c * 8 + 4);
    ushort8v u;
    u[0] = f2bf(v0.x); u[1] = f2bf(v0.y); u[2] = f2bf(v0.z); u[3] = f2bf(v0.w);
    u[4] = f2bf(v1.x); u[5] = f2bf(v1.y); u[6] = f2bf(v1.z); u[7] = f2bf(v1.w);
    *(ushort8v*)(dst + (size_t)c * 8) = u;
}

// ---------------------------------------------------------------------------
// K1: wave-parallel top-5. One wave per (s, b); 16 distances per lane in
// registers; 5 rounds of {register argmin + shfl_xor butterfly}; no barriers.
// Block = 4 waves; all waves in a block share b (2048 blocks, b = wg>>10).
// ---------------------------------------------------------------------------
__global__ __launch_bounds__(256) void topk_scatter(const float* __restrict__ srcp,
                                                    const float* __restrict__ tgtp,
                                                    int* __restrict__ row_cnt,
                                                    int* __restrict__ row_list) {
    const int w = threadIdx.x >> 6, lane = threadIdx.x & 63;
    const int wg = blockIdx.x * 4 + w;          // 0..8191
    const int s = wg & 1023, b = wg >> 10;

    const float sx = srcp[((size_t)s * BATCH + b) * 3 + 0];
    const float sy = srcp[((size_t)s * BATCH + b) * 3 + 1];
    const float sz = srcp[((size_t)s * BATCH + b) * 3 + 2];

    float dv[16];
    #pragma unroll
    for (int i = 0; i < 16; ++i) {
        const int t = i * 64 + lane;
        const float dx = tgtp[((size_t)t * BATCH + b) * 3 + 0] - sx;
        const float dy = tgtp[((size_t)t * BATCH + b) * 3 + 1] - sy;
        const float dz = tgtp[((size_t)t * BATCH + b) * 3 + 2] - sz;
        dv[i] = dx * dx + dy * dy + dz * dz;
    }

    #pragma unroll
    for (int k = 0; k < 5; ++k) {
        float bvv = FLTMAX;
        int   bii = 0x7fffffff;
        #pragma unroll
        for (int i = 0; i < 16; ++i) {
            // strict <: within a lane, lower i (= lower t) wins ties
            if (dv[i] < bvv) { bvv = dv[i]; bii = i * 64 + lane; }
        }
        #pragma unroll
        for (int off = 1; off < 64; off <<= 1) {
            const float ov = __shfl_xor(bvv, off);
            const int   oi = __shfl_xor(bii, off);
            if (ov < bvv || (ov == bvv && oi < bii)) { bvv = ov; bii = oi; }
        }
        // invalidate winner in its owner lane (compile-time indices only)
        if (lane == (bii & 63)) {
            #pragma unroll
            for (int i = 0; i < 16; ++i)
                if (bii == i * 64 + lane) dv[i] = FLTMAX;
        }
        if (lane == 0) {
            const int pos = atomicAdd(&row_cnt[b * NSEQ + bii], 1);
            if (pos < CAP) row_list[((size_t)b * NSEQ + bii) * CAP + pos] = s;
        }
    }
}

// ---------------------------------------------------------------------------
// MFMA GEMM core: out = (A @ W^T + bias) * scale
// Tile 128x64, BK=32, 4 waves 2x2, wave = 64x32 = 4x2 16x16x32 fragments.
// LDS: A [128][32] bf16 @0 (8KB), B [64][32] bf16 @8192 (4KB).
// XOR swizzle: 16B chunk' = chunk ^ ((row>>1)&3).
// AMODE 0: A fp32, reg-staged + converted.  AMODE 1: A bf16 via global_load_lds.
// OMODE 0: write (b,t,c).  OMODE 1: write flat (r,c).
// ---------------------------------------------------------------------------
template<int AMODE, int OMODE>
__device__ inline void gemm_body(const void* __restrict__ Ap,
                                 const unsigned short* __restrict__ Wbf,
                                 const float* __restrict__ bias,
                                 float* __restrict__ out,
                                 float scale) {
    __shared__ __align__(16) char smem[12288];
    const int tid = threadIdx.x;
    const int l = tid & 63, w = tid >> 6;
    const int m0 = blockIdx.x * 128, n0 = blockIdx.y * 64;
    const int wr = (w >> 1) * 64, wc = (w & 1) * 32;
    const int lr = l & 15, g = l >> 4;

    f32x4 acc[4][2] = {};

    const int rowB = w * 16 + (l >> 2);
    const int gkB  = (l & 3) ^ ((rowB >> 1) & 3);
    const unsigned short* bsrc = Wbf + (size_t)(n0 + rowB) * CMODEL + gkB * 8;
    char* bdst = smem + 8192 + w * 1024;

    const float* asrc0 = nullptr; const float* asrc1 = nullptr;
    char* adst0 = nullptr; char* adst1 = nullptr;
    const unsigned short* asrcW0 = nullptr; const unsigned short* asrcW1 = nullptr;
    char* adstW0 = nullptr; char* adstW1 = nullptr;
    if constexpr (AMODE == 0) {
        const int rowA = tid >> 2;
        const int slA  = tid & 3;
        const int gkA  = slA ^ ((rowA >> 1) & 3);
        asrc0 = (const float*)Ap + (size_t)(m0 + rowA) * CMODEL + gkA * 8;
        asrc1 = asrc0 + (size_t)64 * CMODEL;
        adst0 = smem + rowA * 64 + slA * 16;
        adst1 = adst0 + 64 * 64;
    } else {
        const unsigned short* Abf = (const unsigned short*)Ap;
        const int rA0 = w * 16 + (l >> 2);
        const int gk0 = (l & 3) ^ ((rA0 >> 1) & 3);
        asrcW0 = Abf + (size_t)(m0 + rA0) * CMODEL + gk0 * 8;
        asrcW1 = asrcW0 + (size_t)64 * CMODEL;
        adstW0 = smem + w * 1024;
        adstW1 = adstW0 + 4096;
    }

    for (int k0 = 0; k0 < CMODEL; k0 += 32) {
        float4 a00, a01, a10, a11;
        if constexpr (AMODE == 0) {
            a00 = *(const float4*)(asrc0 + k0);
            a01 = *(const float4*)(asrc0 + k0 + 4);
            a10 = *(const float4*)(asrc1 + k0);
            a11 = *(const float4*)(asrc1 + k0 + 4);
        }
        __syncthreads();

        __builtin_amdgcn_global_load_lds(
            (const __attribute__((address_space(1))) void*)(bsrc + k0),
            (__attribute__((address_space(3))) void*)bdst, 16, 0, 0);

        if constexpr (AMODE == 0) {
            ushort8v u0, u1;
            u0[0] = f2bf(a00.x); u0[1] = f2bf(a00.y); u0[2] = f2bf(a00.z); u0[3] = f2bf(a00.w);
            u0[4] = f2bf(a01.x); u0[5] = f2bf(a01.y); u0[6] = f2bf(a01.z); u0[7] = f2bf(a01.w);
            u1[0] = f2bf(a10.x); u1[1] = f2bf(a10.y); u1[2] = f2bf(a10.z); u1[3] = f2bf(a10.w);
            u1[4] = f2bf(a11.x); u1[5] = f2bf(a11.y); u1[6] = f2bf(a11.z); u1[7] = f2bf(a11.w);
            *(ushort8v*)adst0 = u0;
            *(ushort8v*)adst1 = u1;
        } else {
            __builtin_amdgcn_global_load_lds(
                (const __attribute__((address_space(1))) void*)(asrcW0 + k0),
                (__attribute__((address_space(3))) void*)adstW0, 16, 0, 0);
            __builtin_amdgcn_global_load_lds(
                (const __attribute__((address_space(1))) void*)(asrcW1 + k0),
                (__attribute__((address_space(3))) void*)adstW1, 16, 0, 0);
        }
        __syncthreads();

        bf16x8 af[4], bfr[2];
        #pragma unroll
        for (int i = 0; i < 4; ++i) {
            const int ra = wr + i * 16 + lr;
            af[i] = *(const bf16x8*)(smem + ra * 64 + ((g ^ ((ra >> 1) & 3)) << 4));
        }
        #pragma unroll
        for (int j = 0; j < 2; ++j) {
            const int rb = wc + j * 16 + lr;
            bfr[j] = *(const bf16x8*)(smem + 8192 + rb * 64 + ((g ^ ((rb >> 1) & 3)) << 4));
        }
        #pragma unroll
        for (int i = 0; i < 4; ++i)
            #pragma unroll
            for (int j = 0; j < 2; ++j)
                acc[i][j] = __builtin_amdgcn_mfma_f32_16x16x32_bf16(af[i], bfr[j], acc[i][j], 0, 0, 0);
    }

    #pragma unroll
    for (int i = 0; i < 4; ++i) {
        #pragma unroll
        for (int j = 0; j < 2; ++j) {
            const int col = n0 + wc + j * 16 + lr;
            const float bcol = bias[col];
            #pragma unroll
            for (int r = 0; r < 4; ++r) {
                const int row = m0 + wr + i * 16 + g * 4 + r;
                const float val = (acc[i][j][r] + bcol) * scale;
                if constexpr (OMODE == 0) {
                    const int t = row >> 3, bb = row & 7;
                    out[((size_t)(bb * NSEQ + t)) * CMODEL + col] = val;
                } else {
                    out[(size_t)row * CMODEL + col] = val;
                }
            }
        }
    }
}

// fused q/k/v projection: blockIdx.z selects the problem
__global__ __launch_bounds__(256, 2) void gemm_proj(const float* __restrict__ Aq,
                                                    const float* __restrict__ Ak,
                                                    const float* __restrict__ Av,
                                                    const unsigned short* __restrict__ Wq,
                                                    const unsigned short* __restrict__ Wk,
                                                    const unsigned short* __restrict__ Wv,
                                                    const float* __restrict__ bq,
                                                    const float* __restrict__ bk,
                                                    const float* __restrict__ bv,
                                                    float* __restrict__ oq,
                                                    float* __restrict__ ok,
                                                    float* __restrict__ ov) {
    const int z = blockIdx.z;
    const float* A = z == 0 ? Aq : z == 1 ? Ak : Av;
    const unsigned short* W = z == 0 ? Wq : z == 1 ? Wk : Wv;
    const float* bi = z == 0 ? bq : z == 1 ? bk : bv;
    float* o = z == 0 ? oq : z == 1 ? ok : ov;
    const float sc = z == 0 ? 0.125f : 1.0f;
    gemm_body<0, 0>(A, W, bi, o, sc);
}

__global__ __launch_bounds__(256, 2) void gemm_out(const unsigned short* __restrict__ Abf,
                                                   const unsigned short* __restrict__ Wbf,
                                                   const float* __restrict__ bias,
                                                   float* __restrict__ out) {
    gemm_body<1, 1>(Abf, Wbf, bias, out, 1.0f);
}

// ---------------------------------------------------------------------------
// K3: v_mean partials — vm[b][c] += (1/1024) * sum over 64 t-rows.
// ---------------------------------------------------------------------------
__global__ __launch_bounds__(512) void v_mean_k(const float* __restrict__ v,
                                                float* __restrict__ vm) {
    const int b = blockIdx.x;
    const int chunk = blockIdx.y;
    const int c = threadIdx.x;
    float s = 0.f;
    const int t0 = chunk * 64;
    for (int t = 0; t < 64; ++t)
        s += v[((size_t)b * NSEQ + t0 + t) * CMODEL + c];
    atomicAdd(&vm[b * CMODEL + c], s * (1.f / (float)NSEQ));
}

// ---------------------------------------------------------------------------
// K4: sparse attention + attn-row fill. One block per (t, b).
// ---------------------------------------------------------------------------
__global__ __launch_bounds__(256) void sparse_attn(const float* __restrict__ q_ws,
                                                   const float* __restrict__ k_ws,
                                                   const float* __restrict__ v_ws,
                                                   const int* __restrict__ row_cnt,
                                                   const int* __restrict__ row_list,
                                                   const float* __restrict__ vm,
                                                   unsigned short* __restrict__ ctx,
                                                   float* __restrict__ attn_out) {
    const int t = blockIdx.x;
    const int b = blockIdx.y;
    const int tid = threadIdx.x;

    int cnt = row_cnt[b * NSEQ + t];
    if (cnt > CAP) cnt = CAP;

    float* arow = attn_out + ((size_t)b * NSEQ + t) * NSEQ;

    if (cnt == 0) {
        const float u = 1.f / (float)NSEQ;
        const float4 uv = {u, u, u, u};
        ((float4*)arow)[tid] = uv;                       // 256 * 16B = full row
        for (int c = tid; c < CMODEL; c += 256)
            ctx[((size_t)t * BATCH + b) * CMODEL + c] = f2bf(vm[b * CMODEL + c]);
        return;
    }

    {   // zero the full attention row (scatter writes come after barriers below)
        const float4 zv = {0.f, 0.f, 0.f, 0.f};
        ((float4*)arow)[tid] = zv;
    }

    __shared__ float qs[CMODEL];
    __shared__ float esc[CAP][8];
    __shared__ float denom[8];
    __shared__ int   slist[CAP];

    if (tid < 8) denom[tid] = 0.f;
    if (tid < cnt) slist[tid] = row_list[((size_t)b * NSEQ + t) * CAP + tid];
    {
        const float2 qv = *(const float2*)(q_ws + ((size_t)b * NSEQ + t) * CMODEL + tid * 2);
        qs[tid * 2] = qv.x; qs[tid * 2 + 1] = qv.y;
    }
    __syncthreads();

    const int wid = tid >> 6, lane = tid & 63;
    for (int i = wid; i < cnt; i += 4) {
        const int s = slist[i];
        const float* krow = k_ws + ((size_t)b * NSEQ + s) * CMODEL + lane * 8;
        const float* qrow = qs + lane * 8;
        float part = 0.f;
        #pragma unroll
        for (int j = 0; j < 8; ++j) part += qrow[j] * krow[j];
        part += __shfl_xor(part, 1);
        part += __shfl_xor(part, 2);
        part += __shfl_xor(part, 4);
        if ((lane & 7) == 0) {
            const int h = lane >> 3;
            const float e = __expf(part);
            esc[i][h] = e;
            atomicAdd(&denom[h], e);
        }
    }
    __syncthreads();

    for (int x = tid; x < cnt * 8; x += 256)
        esc[x >> 3][x & 7] /= denom[x & 7];
    __syncthreads();

    for (int i = tid; i < cnt; i += 256) {
        float pm = 0.f;
        #pragma unroll
        for (int h = 0; h < 8; ++h) pm += esc[i][h];
        arow[slist[i]] = pm * 0.125f;
    }

    const int c0 = tid * 2;
    const int h0 = c0 >> 6;
    float acc0 = 0.f, acc1 = 0.f;
    for (int i = 0; i < cnt; ++i) {
        const int s = slist[i];
        const float p = esc[i][h0];
        const float2 vv = *(const float2*)(v_ws + ((size_t)b * NSEQ + s) * CMODEL + c0);
        acc0 += p * vv.x; acc1 += p * vv.y;
    }
    unsigned short* crow = ctx + ((size_t)t * BATCH + b) * CMODEL;
    ushort2v cv; cv[0] = f2bf(acc0); cv[1] = f2bf(acc1);
    *(ushort2v*)(crow + c0) = cv;
}

// ---------------------------------------------------------------------------
extern "C" void kernel_launch(void* const* d_in, const int* in_sizes, int n_in,
                              void* d_out, int out_size, void* d_ws, size_t ws_size,
                              hipStream_t stream) {
    (void)in_sizes; (void)n_in; (void)out_size; (void)ws_size;

    const float* query = (const float*)d_in[0];
    const float* key_t = (const float*)d_in[1];
    const float* value = (const float*)d_in[2];
    const float* srcp  = (const float*)d_in[3];
    const float* tgtp  = (const float*)d_in[4];
    const float* Wq    = (const float*)d_in[5];
    const float* Wk    = (const float*)d_in[6];
    const float* Wv    = (const float*)d_in[7];
    const float* bq    = (const float*)d_in[8];
    const float* bk    = (const float*)d_in[9];
    const float* bv    = (const float*)d_in[10];
    const float* Wo    = (const float*)d_in[11];
    const float* bo    = (const float*)d_in[12];

    float* out      = (float*)d_out;                          // (N,B,C)
    float* attn_out = out + (size_t)NSEQ * BATCH * CMODEL;    // (B,N,N)

    const size_t NBC = (size_t)BATCH * NSEQ * CMODEL;         // 4,194,304
    const size_t WSZ = (size_t)CMODEL * CMODEL;               // 262,144
    float* q_ws = (float*)d_ws;
    float* k_ws = q_ws + NBC;
    float* v_ws = k_ws + NBC;
    unsigned short* ctxbf = (unsigned short*)(v_ws + NBC);
    unsigned short* wqbf  = ctxbf + NBC;
    unsigned short* wkbf  = wqbf + WSZ;
    unsigned short* wvbf  = wkbf + WSZ;
    unsigned short* wobf  = wvbf + WSZ;
    int*   row_cnt  = (int*)(wobf + WSZ);                     // 8192 ints
    float* vm       = (float*)(row_cnt + BATCH * NSEQ);       // 4096 floats (contiguous)
    int*   row_list = (int*)(vm + BATCH * CMODEL);            // 8192*CAP ints

    convert_w<<<560, 256, 0, stream>>>(Wq, Wk, Wv, Wo, wqbf, wkbf, wvbf, wobf,
                                       (unsigned int*)row_cnt);

    topk_scatter<<<2048, 256, 0, stream>>>(srcp, tgtp, row_cnt, row_list);

    gemm_proj<<<dim3(64, 8, 3), 256, 0, stream>>>(query, key_t, value,
                                                  wqbf, wkbf, wvbf,
                                                  bq, bk, bv,
                                                  q_ws, k_ws, v_ws);

    v_mean_k<<<dim3(BATCH, 16), 512, 0, stream>>>(v_ws, vm);

    sparse_attn<<<dim3(NSEQ, BATCH), 256, 0, stream>>>(q_ws, k_ws, v_ws, row_cnt,
                                                       row_list, vm, ctxbf, attn_out);

    gemm_out<<<dim3(64, 8), 256, 0, stream>>>(ctxbf, wobf, bo, out);
}

// Round 5
// 94.203 us; speedup vs baseline: 11.1312x; 1.0777x over previous
//
#include <hip/hip_runtime.h>
#include <cstdint>
#include <cstddef>

#define NSEQ 1024
#define BATCH 8
#define CMODEL 512
#define NHEAD 8
#define HDIM 64
#define CAP 64
#define FLTMAX 3.402823466e+38f

typedef short bf16x8 __attribute__((ext_vector_type(8)));
typedef float f32x4 __attribute__((ext_vector_type(4)));
typedef unsigned short ushort8v __attribute__((ext_vector_type(8)));
typedef unsigned short ushort2v __attribute__((ext_vector_type(2)));

__device__ inline unsigned short f2bf(float f) {
    unsigned int u = __builtin_bit_cast(unsigned int, f);
    u += 0x7fffu + ((u >> 16) & 1u);
    return (unsigned short)(u >> 16);
}
__device__ inline float bf2f(unsigned short u) {
    return __builtin_bit_cast(float, (unsigned int)u << 16);
}

#define GLDS16(gsrc, ldst) \
    __builtin_amdgcn_global_load_lds((const __attribute__((address_space(1))) void*)(gsrc), \
                                     (__attribute__((address_space(3))) void*)(ldst), 16, 0, 0)

// ---------------------------------------------------------------------------
// K0: convert 4 weight matrices fp32->bf16 (blocks 0..511); zero row_cnt+vm
// (blocks 512..559).
// ---------------------------------------------------------------------------
__global__ __launch_bounds__(256) void convert_w(const float* __restrict__ w0,
                                                 const float* __restrict__ w1,
                                                 const float* __restrict__ w2,
                                                 const float* __restrict__ w3,
                                                 unsigned short* __restrict__ o0,
                                                 unsigned short* __restrict__ o1,
                                                 unsigned short* __restrict__ o2,
                                                 unsigned short* __restrict__ o3,
                                                 unsigned int* __restrict__ zp) {
    if (blockIdx.x >= 512) {
        const int zi = (blockIdx.x - 512) * 256 + threadIdx.x;   // < 12288
        zp[zi] = 0u;
        return;
    }
    const int idx = blockIdx.x * 256 + threadIdx.x;
    const int rgn = idx >> 15;
    const int c   = idx & 32767;
    const float* src = rgn == 0 ? w0 : rgn == 1 ? w1 : rgn == 2 ? w2 : w3;
    unsigned short* dst = rgn == 0 ? o0 : rgn == 1 ? o1 : rgn == 2 ? o2 : o3;
    const float4 v0 = *(const float4*)(src + (size_t)c * 8);
    const float4 v1 = *(const float4*)(src + (size_t)c * 8 + 4);
    ushort8v u;
    u[0] = f2bf(v0.x); u[1] = f2bf(v0.y); u[2] = f2bf(v0.z); u[3] = f2bf(v0.w);
    u[4] = f2bf(v1.x); u[5] = f2bf(v1.y); u[6] = f2bf(v1.z); u[7] = f2bf(v1.w);
    *(ushort8v*)(dst + (size_t)c * 8) = u;
}

// ---------------------------------------------------------------------------
// K1: wave-parallel top-5. One wave per (s, b); no barriers, no LDS.
// ---------------------------------------------------------------------------
__global__ __launch_bounds__(256) void topk_scatter(const float* __restrict__ srcp,
                                                    const float* __restrict__ tgtp,
                                                    int* __restrict__ row_cnt,
                                                    int* __restrict__ row_list) {
    const int w = threadIdx.x >> 6, lane = threadIdx.x & 63;
    const int wg = blockIdx.x * 4 + w;          // 0..8191
    const int s = wg & 1023, b = wg >> 10;

    const float sx = srcp[((size_t)s * BATCH + b) * 3 + 0];
    const float sy = srcp[((size_t)s * BATCH + b) * 3 + 1];
    const float sz = srcp[((size_t)s * BATCH + b) * 3 + 2];

    float dv[16];
    #pragma unroll
    for (int i = 0; i < 16; ++i) {
        const int t = i * 64 + lane;
        const float dx = tgtp[((size_t)t * BATCH + b) * 3 + 0] - sx;
        const float dy = tgtp[((size_t)t * BATCH + b) * 3 + 1] - sy;
        const float dz = tgtp[((size_t)t * BATCH + b) * 3 + 2] - sz;
        dv[i] = dx * dx + dy * dy + dz * dz;
    }

    #pragma unroll
    for (int k = 0; k < 5; ++k) {
        float bvv = FLTMAX;
        int   bii = 0x7fffffff;
        #pragma unroll
        for (int i = 0; i < 16; ++i) {
            if (dv[i] < bvv) { bvv = dv[i]; bii = i * 64 + lane; }
        }
        #pragma unroll
        for (int off = 1; off < 64; off <<= 1) {
            const float ov = __shfl_xor(bvv, off);
            const int   oi = __shfl_xor(bii, off);
            if (ov < bvv || (ov == bvv && oi < bii)) { bvv = ov; bii = oi; }
        }
        if (lane == (bii & 63)) {
            #pragma unroll
            for (int i = 0; i < 16; ++i)
                if (bii == i * 64 + lane) dv[i] = FLTMAX;
        }
        if (lane == 0) {
            const int pos = atomicAdd(&row_cnt[b * NSEQ + bii], 1);
            if (pos < CAP) row_list[((size_t)b * NSEQ + bii) * CAP + pos] = s;
        }
    }
}

// ---------------------------------------------------------------------------
// MFMA GEMM core, double-buffered: out = (A @ W^T + bias) * scale
// Tile 128x64, BK=32, 4 waves 2x2, wave = 4x2 16x16x32 fragments.
// LDS: 2 buffers x (A [128][32]bf16 8KB + B [64][32]bf16 4KB) = 24 KB.
// XOR swizzle: 16B chunk' = chunk ^ ((row>>1)&3).
// Pipeline: per K-step {STAGE(nxt); COMPUTE(cur); barrier} — the staging
// loads have the compute phase to land before the barrier's vmcnt drain.
// AMODE 0: A fp32, reg-prefetched one step ahead + converted (T14 split).
// AMODE 1: A bf16 via global_load_lds.
// OMODE 0: write bf16 (b,t,c).  OMODE 1: write fp32 flat (r,c).
// ---------------------------------------------------------------------------
template<int AMODE, int OMODE>
__device__ inline void gemm_body(const void* __restrict__ Ap,
                                 const unsigned short* __restrict__ Wbf,
                                 const float* __restrict__ bias,
                                 void* __restrict__ outp,
                                 float scale) {
    __shared__ __align__(16) char smem[24576];
    const int tid = threadIdx.x;
    const int l = tid & 63, w = tid >> 6;
    const int m0 = blockIdx.x * 128, n0 = blockIdx.y * 64;
    const int wr = (w >> 1) * 64, wc = (w & 1) * 32;
    const int lr = l & 15, g = l >> 4;

    f32x4 acc[4][2] = {};

    // B staging (per-K-step: 256 lanes x 16B = 4KB tile)
    const int rowB = w * 16 + (l >> 2);
    const int gkB  = (l & 3) ^ ((rowB >> 1) & 3);
    const unsigned short* bsrc = Wbf + (size_t)(n0 + rowB) * CMODEL + gkB * 8;
    const int boff = 8192 + w * 1024;            // wave-uniform dst offset

    // A staging
    const float* asrc0 = nullptr; const float* asrc1 = nullptr;
    int adoff0 = 0, adoff1 = 0;
    const unsigned short* asrcW0 = nullptr; const unsigned short* asrcW1 = nullptr;
    int adWoff0 = 0, adWoff1 = 0;
    if constexpr (AMODE == 0) {
        const int rowA = tid >> 2;
        const int slA  = tid & 3;
        const int gkA  = slA ^ ((rowA >> 1) & 3);   // same for rowA+64
        asrc0 = (const float*)Ap + (size_t)(m0 + rowA) * CMODEL + gkA * 8;
        asrc1 = asrc0 + (size_t)64 * CMODEL;
        adoff0 = rowA * 64 + slA * 16;
        adoff1 = adoff0 + 4096;
    } else {
        const unsigned short* Abf = (const unsigned short*)Ap;
        const int rA0 = w * 16 + (l >> 2);
        const int gk0 = (l & 3) ^ ((rA0 >> 1) & 3);
        asrcW0 = Abf + (size_t)(m0 + rA0) * CMODEL + gk0 * 8;
        asrcW1 = asrcW0 + (size_t)64 * CMODEL;
        adWoff0 = w * 1024;
        adWoff1 = adWoff0 + 4096;
    }

    float4 a00, a01, a10, a11;     // A reg prefetch (AMODE 0)

    auto LOADA = [&](int k0) {
        a00 = *(const float4*)(asrc0 + k0); a01 = *(const float4*)(asrc0 + k0 + 4);
        a10 = *(const float4*)(asrc1 + k0); a11 = *(const float4*)(asrc1 + k0 + 4);
    };
    auto CVTSTORE = [&](int buf) {
        ushort8v u0, u1;
        u0[0] = f2bf(a00.x); u0[1] = f2bf(a00.y); u0[2] = f2bf(a00.z); u0[3] = f2bf(a00.w);
        u0[4] = f2bf(a01.x); u0[5] = f2bf(a01.y); u0[6] = f2bf(a01.z); u0[7] = f2bf(a01.w);
        u1[0] = f2bf(a10.x); u1[1] = f2bf(a10.y); u1[2] = f2bf(a10.z); u1[3] = f2bf(a10.w);
        u1[4] = f2bf(a11.x); u1[5] = f2bf(a11.y); u1[6] = f2bf(a11.z); u1[7] = f2bf(a11.w);
        char* bb = smem + buf * 12288;
        *(ushort8v*)(bb + adoff0) = u0;
        *(ushort8v*)(bb + adoff1) = u1;
    };
    auto STAGE = [&](int k0, int buf) {
        char* bb = smem + buf * 12288;
        GLDS16(bsrc + k0, bb + boff);
        if constexpr (AMODE == 1) {
            GLDS16(asrcW0 + k0, bb + adWoff0);
            GLDS16(asrcW1 + k0, bb + adWoff1);
        }
    };

    // prologue: fill buffer 0 with tile 0; prefetch A-tile 1 to regs
    if constexpr (AMODE == 0) {
        LOADA(0);
        STAGE(0, 0);
        CVTSTORE(0);
        LOADA(32);
    } else {
        STAGE(0, 0);
    }
    __syncthreads();

    for (int t = 0; t < 16; ++t) {
        const int cur = t & 1;
        if (t < 15) {
            STAGE((t + 1) * 32, cur ^ 1);
            if constexpr (AMODE == 0) {
                CVTSTORE(cur ^ 1);            // regs hold tile t+1
                if (t < 14) LOADA((t + 2) * 32);
            }
        }
        char* base = smem + cur * 12288;
        bf16x8 af[4], bfr[2];
        #pragma unroll
        for (int i = 0; i < 4; ++i) {
            const int ra = wr + i * 16 + lr;
            af[i] = *(const bf16x8*)(base + ra * 64 + ((g ^ ((ra >> 1) & 3)) << 4));
        }
        #pragma unroll
        for (int j = 0; j < 2; ++j) {
            const int rb = wc + j * 16 + lr;
            bfr[j] = *(const bf16x8*)(base + 8192 + rb * 64 + ((g ^ ((rb >> 1) & 3)) << 4));
        }
        #pragma unroll
        for (int i = 0; i < 4; ++i)
            #pragma unroll
            for (int j = 0; j < 2; ++j)
                acc[i][j] = __builtin_amdgcn_mfma_f32_16x16x32_bf16(af[i], bfr[j], acc[i][j], 0, 0, 0);
        __syncthreads();
    }

    #pragma unroll
    for (int i = 0; i < 4; ++i) {
        #pragma unroll
        for (int j = 0; j < 2; ++j) {
            const int col = n0 + wc + j * 16 + lr;
            const float bcol = bias[col];
            #pragma unroll
            for (int r = 0; r < 4; ++r) {
                const int row = m0 + wr + i * 16 + g * 4 + r;
                const float val = (acc[i][j][r] + bcol) * scale;
                if constexpr (OMODE == 0) {
                    const int t = row >> 3, bb = row & 7;
                    ((unsigned short*)outp)[((size_t)(bb * NSEQ + t)) * CMODEL + col] = f2bf(val);
                } else {
                    ((float*)outp)[(size_t)row * CMODEL + col] = val;
                }
            }
        }
    }
}

// fused q/k/v projection: blockIdx.z selects the problem
__global__ __launch_bounds__(256, 4) void gemm_proj(const float* __restrict__ Aq,
                                                    const float* __restrict__ Ak,
                                                    const float* __restrict__ Av,
                                                    const unsigned short* __restrict__ Wq,
                                                    const unsigned short* __restrict__ Wk,
                                                    const unsigned short* __restrict__ Wv,
                                                    const float* __restrict__ bq,
                                                    const float* __restrict__ bk,
                                                    const float* __restrict__ bv,
                                                    unsigned short* __restrict__ oq,
                                                    unsigned short* __restrict__ ok,
                                                    unsigned short* __restrict__ ov) {
    const int z = blockIdx.z;
    const float* A = z == 0 ? Aq : z == 1 ? Ak : Av;
    const unsigned short* W = z == 0 ? Wq : z == 1 ? Wk : Wv;
    const float* bi = z == 0 ? bq : z == 1 ? bk : bv;
    unsigned short* o = z == 0 ? oq : z == 1 ? ok : ov;
    const float sc = z == 0 ? 0.125f : 1.0f;
    gemm_body<0, 0>(A, W, bi, o, sc);
}

__global__ __launch_bounds__(256, 4) void gemm_out(const unsigned short* __restrict__ Abf,
                                                   const unsigned short* __restrict__ Wbf,
                                                   const float* __restrict__ bias,
                                                   float* __restrict__ out) {
    gemm_body<1, 1>(Abf, Wbf, bias, out, 1.0f);
}

// ---------------------------------------------------------------------------
// K3: v_mean partials — vm[b][c] += (1/1024) * sum over 64 t-rows (bf16 v).
// ---------------------------------------------------------------------------
__global__ __launch_bounds__(512) void v_mean_k(const unsigned short* __restrict__ v,
                                                float* __restrict__ vm) {
    const int b = blockIdx.x;
    const int chunk = blockIdx.y;
    const int c = threadIdx.x;
    float s = 0.f;
    const int t0 = chunk * 64;
    for (int t = 0; t < 64; ++t)
        s += bf2f(v[((size_t)b * NSEQ + t0 + t) * CMODEL + c]);
    atomicAdd(&vm[b * CMODEL + c], s * (1.f / (float)NSEQ));
}

// ---------------------------------------------------------------------------
// K4: sparse attention + attn-row fill. One block per (t, b). bf16 q/k/v.
// ---------------------------------------------------------------------------
__global__ __launch_bounds__(256) void sparse_attn(const unsigned short* __restrict__ q_ws,
                                                   const unsigned short* __restrict__ k_ws,
                                                   const unsigned short* __restrict__ v_ws,
                                                   const int* __restrict__ row_cnt,
                                                   const int* __restrict__ row_list,
                                                   const float* __restrict__ vm,
                                                   unsigned short* __restrict__ ctx,
                                                   float* __restrict__ attn_out) {
    const int t = blockIdx.x;
    const int b = blockIdx.y;
    const int tid = threadIdx.x;

    int cnt = row_cnt[b * NSEQ + t];
    if (cnt > CAP) cnt = CAP;

    float* arow = attn_out + ((size_t)b * NSEQ + t) * NSEQ;

    if (cnt == 0) {
        const float u = 1.f / (float)NSEQ;
        const float4 uv = {u, u, u, u};
        ((float4*)arow)[tid] = uv;
        for (int c = tid; c < CMODEL; c += 256)
            ctx[((size_t)t * BATCH + b) * CMODEL + c] = f2bf(vm[b * CMODEL + c]);
        return;
    }

    {
        const float4 zv = {0.f, 0.f, 0.f, 0.f};
        ((float4*)arow)[tid] = zv;
    }

    __shared__ float qs[CMODEL];
    __shared__ float esc[CAP][8];
    __shared__ float denom[8];
    __shared__ int   slist[CAP];

    if (tid < 8) denom[tid] = 0.f;
    if (tid < cnt) slist[tid] = row_list[((size_t)b * NSEQ + t) * CAP + tid];
    {
        const ushort2v qv = *(const ushort2v*)(q_ws + ((size_t)b * NSEQ + t) * CMODEL + tid * 2);
        qs[tid * 2] = bf2f(qv[0]); qs[tid * 2 + 1] = bf2f(qv[1]);
    }
    __syncthreads();

    const int wid = tid >> 6, lane = tid & 63;
    for (int i = wid; i < cnt; i += 4) {
        const int s = slist[i];
        const ushort8v kv = *(const ushort8v*)(k_ws + ((size_t)b * NSEQ + s) * CMODEL + lane * 8);
        const float* qrow = qs + lane * 8;
        float part = 0.f;
        #pragma unroll
        for (int j = 0; j < 8; ++j) part += qrow[j] * bf2f(kv[j]);
        part += __shfl_xor(part, 1);
        part += __shfl_xor(part, 2);
        part += __shfl_xor(part, 4);
        if ((lane & 7) == 0) {
            const int h = lane >> 3;
            const float e = __expf(part);
            esc[i][h] = e;
            atomicAdd(&denom[h], e);
        }
    }
    __syncthreads();

    for (int x = tid; x < cnt * 8; x += 256)
        esc[x >> 3][x & 7] /= denom[x & 7];
    __syncthreads();

    for (int i = tid; i < cnt; i += 256) {
        float pm = 0.f;
        #pragma unroll
        for (int h = 0; h < 8; ++h) pm += esc[i][h];
        arow[slist[i]] = pm * 0.125f;
    }

    const int c0 = tid * 2;
    const int h0 = c0 >> 6;
    float acc0 = 0.f, acc1 = 0.f;
    for (int i = 0; i < cnt; ++i) {
        const int s = slist[i];
        const float p = esc[i][h0];
        const ushort2v vv = *(const ushort2v*)(v_ws + ((size_t)b * NSEQ + s) * CMODEL + c0);
        acc0 += p * bf2f(vv[0]); acc1 += p * bf2f(vv[1]);
    }
    unsigned short* crow = ctx + ((size_t)t * BATCH + b) * CMODEL;
    ushort2v cv; cv[0] = f2bf(acc0); cv[1] = f2bf(acc1);
    *(ushort2v*)(crow + c0) = cv;
}

// ---------------------------------------------------------------------------
extern "C" void kernel_launch(void* const* d_in, const int* in_sizes, int n_in,
                              void* d_out, int out_size, void* d_ws, size_t ws_size,
                              hipStream_t stream) {
    (void)in_sizes; (void)n_in; (void)out_size; (void)ws_size;

    const float* query = (const float*)d_in[0];
    const float* key_t = (const float*)d_in[1];
    const float* value = (const float*)d_in[2];
    const float* srcp  = (const float*)d_in[3];
    const float* tgtp  = (const float*)d_in[4];
    const float* Wq    = (const float*)d_in[5];
    const float* Wk    = (const float*)d_in[6];
    const float* Wv    = (const float*)d_in[7];
    const float* bq    = (const float*)d_in[8];
    const float* bk    = (const float*)d_in[9];
    const float* bv    = (const float*)d_in[10];
    const float* Wo    = (const float*)d_in[11];
    const float* bo    = (const float*)d_in[12];

    float* out      = (float*)d_out;                          // (N,B,C)
    float* attn_out = out + (size_t)NSEQ * BATCH * CMODEL;    // (B,N,N)

    const size_t NBC = (size_t)BATCH * NSEQ * CMODEL;         // 4,194,304
    const size_t WSZ = (size_t)CMODEL * CMODEL;               // 262,144
    unsigned short* q_ws  = (unsigned short*)d_ws;
    unsigned short* k_ws  = q_ws + NBC;
    unsigned short* v_ws  = k_ws + NBC;
    unsigned short* ctxbf = v_ws + NBC;
    unsigned short* wqbf  = ctxbf + NBC;
    unsigned short* wkbf  = wqbf + WSZ;
    unsigned short* wvbf  = wkbf + WSZ;
    unsigned short* wobf  = wvbf + WSZ;
    int*   row_cnt  = (int*)(wobf + WSZ);                     // 8192 ints
    float* vm       = (float*)(row_cnt + BATCH * NSEQ);       // 4096 floats (contiguous)
    int*   row_list = (int*)(vm + BATCH * CMODEL);            // 8192*CAP ints

    convert_w<<<560, 256, 0, stream>>>(Wq, Wk, Wv, Wo, wqbf, wkbf, wvbf, wobf,
                                       (unsigned int*)row_cnt);

    topk_scatter<<<2048, 256, 0, stream>>>(srcp, tgtp, row_cnt, row_list);

    gemm_proj<<<dim3(64, 8, 3), 256, 0, stream>>>(query, key_t, value,
                                                  wqbf, wkbf, wvbf,
                                                  bq, bk, bv,
                                                  q_ws, k_ws, v_ws);

    v_mean_k<<<dim3(BATCH, 16), 512, 0, stream>>>(v_ws, vm);

    sparse_attn<<<dim3(NSEQ, BATCH), 256, 0, stream>>>(q_ws, k_ws, v_ws, row_cnt,
                                                       row_list, vm, ctxbf, attn_out);

    gemm_out<<<dim3(64, 8), 256, 0, stream>>>(ctxbf, wobf, bo, out);
}

// Round 6
// 90.857 us; speedup vs baseline: 11.5410x; 1.0368x over previous
//
#include <hip/hip_runtime.h>
#include <cstdint>
#include <cstddef>

#define NSEQ 1024
#define BATCH 8
#define CMODEL 512
#define NHEAD 8
#define HDIM 64
#define CAP 64
#define FLTMAX 3.402823466e+38f

typedef short bf16x8 __attribute__((ext_vector_type(8)));
typedef float f32x4 __attribute__((ext_vector_type(4)));
typedef unsigned short ushort8v __attribute__((ext_vector_type(8)));
typedef unsigned short ushort2v __attribute__((ext_vector_type(2)));

__device__ inline unsigned short f2bf(float f) {
    unsigned int u = __builtin_bit_cast(unsigned int, f);
    u += 0x7fffu + ((u >> 16) & 1u);
    return (unsigned short)(u >> 16);
}
__device__ inline float bf2f(unsigned short u) {
    return __builtin_bit_cast(float, (unsigned int)u << 16);
}

#define GLDS16(gsrc, ldst) \
    __builtin_amdgcn_global_load_lds((const __attribute__((address_space(1))) void*)(gsrc), \
                                     (__attribute__((address_space(3))) void*)(ldst), 16, 0, 0)

// ---------------------------------------------------------------------------
// K0: convert query/key_t/value (3 x 4,194,304 f32) + 4 weights (4 x 262,144)
// to bf16, and zero row_cnt+vm (12288 u32). One fused launch.
// idx < 1572864: activations (8 elems/thread); < 1703936: weights; else zero.
// ---------------------------------------------------------------------------
__global__ __launch_bounds__(256) void convert_all(
        const float* __restrict__ a0, const float* __restrict__ a1,
        const float* __restrict__ a2,
        const float* __restrict__ w0, const float* __restrict__ w1,
        const float* __restrict__ w2, const float* __restrict__ w3,
        unsigned short* __restrict__ oa0, unsigned short* __restrict__ oa1,
        unsigned short* __restrict__ oa2,
        unsigned short* __restrict__ ow0, unsigned short* __restrict__ ow1,
        unsigned short* __restrict__ ow2, unsigned short* __restrict__ ow3,
        unsigned int* __restrict__ zp) {
    const unsigned int idx = blockIdx.x * 256 + threadIdx.x;
    if (idx >= 1703936u) { zp[idx - 1703936u] = 0u; return; }
    const float* src; unsigned short* dst; unsigned int c;
    if (idx < 1572864u) {
        const unsigned int seg = idx >> 19; c = idx & 524287u;
        src = seg == 0 ? a0 : seg == 1 ? a1 : a2;
        dst = seg == 0 ? oa0 : seg == 1 ? oa1 : oa2;
    } else {
        const unsigned int rel = idx - 1572864u, seg = rel >> 15; c = rel & 32767u;
        src = seg == 0 ? w0 : seg == 1 ? w1 : seg == 2 ? w2 : w3;
        dst = seg == 0 ? ow0 : seg == 1 ? ow1 : seg == 2 ? ow2 : ow3;
    }
    const float4 v0 = *(const float4*)(src + (size_t)c * 8);
    const float4 v1 = *(const float4*)(src + (size_t)c * 8 + 4);
    ushort8v u;
    u[0] = f2bf(v0.x); u[1] = f2bf(v0.y); u[2] = f2bf(v0.z); u[3] = f2bf(v0.w);
    u[4] = f2bf(v1.x); u[5] = f2bf(v1.y); u[6] = f2bf(v1.z); u[7] = f2bf(v1.w);
    *(ushort8v*)(dst + (size_t)c * 8) = u;
}

// ---------------------------------------------------------------------------
// K1: wave-parallel top-5. One wave per (s, b); no barriers, no LDS.
// ---------------------------------------------------------------------------
__global__ __launch_bounds__(256) void topk_scatter(const float* __restrict__ srcp,
                                                    const float* __restrict__ tgtp,
                                                    int* __restrict__ row_cnt,
                                                    int* __restrict__ row_list) {
    const int w = threadIdx.x >> 6, lane = threadIdx.x & 63;
    const int wg = blockIdx.x * 4 + w;          // 0..8191
    const int s = wg & 1023, b = wg >> 10;

    const float sx = srcp[((size_t)s * BATCH + b) * 3 + 0];
    const float sy = srcp[((size_t)s * BATCH + b) * 3 + 1];
    const float sz = srcp[((size_t)s * BATCH + b) * 3 + 2];

    float dv[16];
    #pragma unroll
    for (int i = 0; i < 16; ++i) {
        const int t = i * 64 + lane;
        const float dx = tgtp[((size_t)t * BATCH + b) * 3 + 0] - sx;
        const float dy = tgtp[((size_t)t * BATCH + b) * 3 + 1] - sy;
        const float dz = tgtp[((size_t)t * BATCH + b) * 3 + 2] - sz;
        dv[i] = dx * dx + dy * dy + dz * dz;
    }

    #pragma unroll
    for (int k = 0; k < 5; ++k) {
        float bvv = FLTMAX;
        int   bii = 0x7fffffff;
        #pragma unroll
        for (int i = 0; i < 16; ++i) {
            if (dv[i] < bvv) { bvv = dv[i]; bii = i * 64 + lane; }
        }
        #pragma unroll
        for (int off = 1; off < 64; off <<= 1) {
            const float ov = __shfl_xor(bvv, off);
            const int   oi = __shfl_xor(bii, off);
            if (ov < bvv || (ov == bvv && oi < bii)) { bvv = ov; bii = oi; }
        }
        if (lane == (bii & 63)) {
            #pragma unroll
            for (int i = 0; i < 16; ++i)
                if (bii == i * 64 + lane) dv[i] = FLTMAX;
        }
        if (lane == 0) {
            const int pos = atomicAdd(&row_cnt[b * NSEQ + bii], 1);
            if (pos < CAP) row_list[((size_t)b * NSEQ + bii) * CAP + pos] = s;
        }
    }
}

// ---------------------------------------------------------------------------
// MFMA GEMM, counted-vmcnt ring-3 pipeline:  out = (A @ W^T + bias) * scale
// A, W bf16. Tile 128x128, BK=32, 4 waves (2x2), wave = 64x64 (4x4 frags).
// LDS: 3 bufs x (A[128][32] + B[128][32]) bf16 = 3 x 16 KB = 48 KB.
// Per iter: s_waitcnt vmcnt(4) [leave next tile in flight]; s_barrier;
// issue GLDS for tile t+2 into buf (t+2)%3; 16 MFMA (setprio-wrapped).
// Buffer safety: writer of buf[(t+2)%3] runs after barrier(t), and all waves
// finished compute(t-1) [same buffer] before reaching barrier(t).
// XOR swizzle: 16B chunk' = chunk ^ ((row>>1)&3)  -> 2-way residual (free).
// OMODE 0: write bf16 (b,t,c).  OMODE 1: write fp32 flat (r,c).
// ---------------------------------------------------------------------------
template<int OMODE>
__device__ inline void gemm_body(const unsigned short* __restrict__ Abf,
                                 const unsigned short* __restrict__ Wbf,
                                 const float* __restrict__ bias,
                                 void* __restrict__ outp, float scale) {
    __shared__ __align__(16) unsigned short smem[3 * 8192];
    const int tid = threadIdx.x;
    const int l = tid & 63, w = tid >> 6;
    const int m0 = blockIdx.x * 128, n0 = blockIdx.y * 128;
    const int wr = (w >> 1) * 64, wc = (w & 1) * 64;
    const int lr = l & 15, g = l >> 4;

    f32x4 acc[4][4] = {};

    // staging: 4 GLDS chunks/thread (A rows 0-63, A rows 64-127, B 0-63, B 64-127)
    const int rowX = tid >> 2;                      // 0..63
    const int kg0  = (tid & 3) ^ ((rowX >> 1) & 3); // pre-swizzled global k-chunk
    const unsigned short* aS0 = Abf + (size_t)(m0 + rowX) * CMODEL + kg0 * 8;
    const unsigned short* aS1 = aS0 + (size_t)64 * CMODEL;
    const unsigned short* bS0 = Wbf + (size_t)(n0 + rowX) * CMODEL + kg0 * 8;
    const unsigned short* bS1 = bS0 + (size_t)64 * CMODEL;
    const int wb = w * 512;                         // wave-uniform LDS elem offset

    auto STAGE = [&](int k0, int buf) {
        unsigned short* bb = smem + buf * 8192;
        GLDS16(aS0 + k0, bb + wb);
        GLDS16(aS1 + k0, bb + 2048 + wb);
        GLDS16(bS0 + k0, bb + 4096 + wb);
        GLDS16(bS1 + k0, bb + 6144 + wb);
    };
    auto COMPUTE = [&](const unsigned short* base) {
        bf16x8 af[4], bg[4];
        #pragma unroll
        for (int i = 0; i < 4; ++i) {
            const int ra = wr + i * 16 + lr;
            af[i] = *(const bf16x8*)(base + ra * 32 + ((g ^ ((ra >> 1) & 3)) << 3));
        }
        #pragma unroll
        for (int j = 0; j < 4; ++j) {
            const int rb = wc + j * 16 + lr;
            bg[j] = *(const bf16x8*)(base + 4096 + rb * 32 + ((g ^ ((rb >> 1) & 3)) << 3));
        }
        __builtin_amdgcn_s_setprio(1);
        #pragma unroll
        for (int i = 0; i < 4; ++i)
            #pragma unroll
            for (int j = 0; j < 4; ++j)
                acc[i][j] = __builtin_amdgcn_mfma_f32_16x16x32_bf16(af[i], bg[j], acc[i][j], 0, 0, 0);
        __builtin_amdgcn_s_setprio(0);
    };

    STAGE(0, 0);
    STAGE(32, 1);

    int cur = 0;
    for (int t = 0; t < 15; ++t) {
        asm volatile("s_waitcnt vmcnt(4)" ::: "memory");
        __builtin_amdgcn_s_barrier();
        if (t < 14) {
            int nb = cur + 2; if (nb >= 3) nb -= 3;
            STAGE((t + 2) * 32, nb);
        }
        COMPUTE(smem + cur * 8192);
        ++cur; if (cur == 3) cur = 0;
    }
    asm volatile("s_waitcnt vmcnt(0)" ::: "memory");
    __builtin_amdgcn_s_barrier();
    COMPUTE(smem + cur * 8192);

    #pragma unroll
    for (int i = 0; i < 4; ++i) {
        #pragma unroll
        for (int j = 0; j < 4; ++j) {
            const int col = n0 + wc + j * 16 + lr;
            const float bcol = bias[col];
            #pragma unroll
            for (int r = 0; r < 4; ++r) {
                const int row = m0 + wr + i * 16 + g * 4 + r;
                const float val = (acc[i][j][r] + bcol) * scale;
                if constexpr (OMODE == 0) {
                    const int t = row >> 3, bb = row & 7;
                    ((unsigned short*)outp)[((size_t)(bb * NSEQ + t)) * CMODEL + col] = f2bf(val);
                } else {
                    ((float*)outp)[(size_t)row * CMODEL + col] = val;
                }
            }
        }
    }
}

// fused q/k/v projection: blockIdx.z selects the problem
__global__ __launch_bounds__(256, 3) void gemm_proj(const unsigned short* __restrict__ Aq,
                                                    const unsigned short* __restrict__ Ak,
                                                    const unsigned short* __restrict__ Av,
                                                    const unsigned short* __restrict__ Wq,
                                                    const unsigned short* __restrict__ Wk,
                                                    const unsigned short* __restrict__ Wv,
                                                    const float* __restrict__ bq,
                                                    const float* __restrict__ bk,
                                                    const float* __restrict__ bv,
                                                    unsigned short* __restrict__ oq,
                                                    unsigned short* __restrict__ ok,
                                                    unsigned short* __restrict__ ov) {
    const int z = blockIdx.z;
    const unsigned short* A = z == 0 ? Aq : z == 1 ? Ak : Av;
    const unsigned short* W = z == 0 ? Wq : z == 1 ? Wk : Wv;
    const float* bi = z == 0 ? bq : z == 1 ? bk : bv;
    unsigned short* o = z == 0 ? oq : z == 1 ? ok : ov;
    const float sc = z == 0 ? 0.125f : 1.0f;
    gemm_body<0>(A, W, bi, o, sc);
}

__global__ __launch_bounds__(256, 3) void gemm_out(const unsigned short* __restrict__ Abf,
                                                   const unsigned short* __restrict__ Wbf,
                                                   const float* __restrict__ bias,
                                                   float* __restrict__ out) {
    gemm_body<1>(Abf, Wbf, bias, out, 1.0f);
}

// ---------------------------------------------------------------------------
// K3: v_mean partials — vm[b][c] += (1/1024) * sum over 64 t-rows (bf16 v).
// ---------------------------------------------------------------------------
__global__ __launch_bounds__(512) void v_mean_k(const unsigned short* __restrict__ v,
                                                float* __restrict__ vm) {
    const int b = blockIdx.x;
    const int chunk = blockIdx.y;
    const int c = threadIdx.x;
    float s = 0.f;
    const int t0 = chunk * 64;
    for (int t = 0; t < 64; ++t)
        s += bf2f(v[((size_t)b * NSEQ + t0 + t) * CMODEL + c]);
    atomicAdd(&vm[b * CMODEL + c], s * (1.f / (float)NSEQ));
}

// ---------------------------------------------------------------------------
// K4: sparse attention + attn-row fill. One block per (t, b). bf16 q/k/v.
// ---------------------------------------------------------------------------
__global__ __launch_bounds__(256) void sparse_attn(const unsigned short* __restrict__ q_ws,
                                                   const unsigned short* __restrict__ k_ws,
                                                   const unsigned short* __restrict__ v_ws,
                                                   const int* __restrict__ row_cnt,
                                                   const int* __restrict__ row_list,
                                                   const float* __restrict__ vm,
                                                   unsigned short* __restrict__ ctx,
                                                   float* __restrict__ attn_out) {
    const int t = blockIdx.x;
    const int b = blockIdx.y;
    const int tid = threadIdx.x;

    int cnt = row_cnt[b * NSEQ + t];
    if (cnt > CAP) cnt = CAP;

    float* arow = attn_out + ((size_t)b * NSEQ + t) * NSEQ;

    if (cnt == 0) {
        const float u = 1.f / (float)NSEQ;
        const float4 uv = {u, u, u, u};
        ((float4*)arow)[tid] = uv;
        for (int c = tid; c < CMODEL; c += 256)
            ctx[((size_t)t * BATCH + b) * CMODEL + c] = f2bf(vm[b * CMODEL + c]);
        return;
    }

    {
        const float4 zv = {0.f, 0.f, 0.f, 0.f};
        ((float4*)arow)[tid] = zv;
    }

    __shared__ float qs[CMODEL];
    __shared__ float esc[CAP][8];
    __shared__ float denom[8];
    __shared__ int   slist[CAP];

    if (tid < 8) denom[tid] = 0.f;
    if (tid < cnt) slist[tid] = row_list[((size_t)b * NSEQ + t) * CAP + tid];
    {
        const ushort2v qv = *(const ushort2v*)(q_ws + ((size_t)b * NSEQ + t) * CMODEL + tid * 2);
        qs[tid * 2] = bf2f(qv[0]); qs[tid * 2 + 1] = bf2f(qv[1]);
    }
    __syncthreads();

    const int wid = tid >> 6, lane = tid & 63;
    for (int i = wid; i < cnt; i += 4) {
        const int s = slist[i];
        const ushort8v kv = *(const ushort8v*)(k_ws + ((size_t)b * NSEQ + s) * CMODEL + lane * 8);
        const float* qrow = qs + lane * 8;
        float part = 0.f;
        #pragma unroll
        for (int j = 0; j < 8; ++j) part += qrow[j] * bf2f(kv[j]);
        part += __shfl_xor(part, 1);
        part += __shfl_xor(part, 2);
        part += __shfl_xor(part, 4);
        if ((lane & 7) == 0) {
            const int h = lane >> 3;
            const float e = __expf(part);
            esc[i][h] = e;
            atomicAdd(&denom[h], e);
        }
    }
    __syncthreads();

    for (int x = tid; x < cnt * 8; x += 256)
        esc[x >> 3][x & 7] /= denom[x & 7];
    __syncthreads();

    for (int i = tid; i < cnt; i += 256) {
        float pm = 0.f;
        #pragma unroll
        for (int h = 0; h < 8; ++h) pm += esc[i][h];
        arow[slist[i]] = pm * 0.125f;
    }

    const int c0 = tid * 2;
    const int h0 = c0 >> 6;
    float acc0 = 0.f, acc1 = 0.f;
    for (int i = 0; i < cnt; ++i) {
        const int s = slist[i];
        const float p = esc[i][h0];
        const ushort2v vv = *(const ushort2v*)(v_ws + ((size_t)b * NSEQ + s) * CMODEL + c0);
        acc0 += p * bf2f(vv[0]); acc1 += p * bf2f(vv[1]);
    }
    unsigned short* crow = ctx + ((size_t)t * BATCH + b) * CMODEL;
    ushort2v cv; cv[0] = f2bf(acc0); cv[1] = f2bf(acc1);
    *(ushort2v*)(crow + c0) = cv;
}

// ---------------------------------------------------------------------------
extern "C" void kernel_launch(void* const* d_in, const int* in_sizes, int n_in,
                              void* d_out, int out_size, void* d_ws, size_t ws_size,
                              hipStream_t stream) {
    (void)in_sizes; (void)n_in; (void)out_size; (void)ws_size;

    const float* query = (const float*)d_in[0];
    const float* key_t = (const float*)d_in[1];
    const float* value = (const float*)d_in[2];
    const float* srcp  = (const float*)d_in[3];
    const float* tgtp  = (const float*)d_in[4];
    const float* Wq    = (const float*)d_in[5];
    const float* Wk    = (const float*)d_in[6];
    const float* Wv    = (const float*)d_in[7];
    const float* bq    = (const float*)d_in[8];
    const float* bk    = (const float*)d_in[9];
    const float* bv    = (const float*)d_in[10];
    const float* Wo    = (const float*)d_in[11];
    const float* bo    = (const float*)d_in[12];

    float* out      = (float*)d_out;                          // (N,B,C)
    float* attn_out = out + (size_t)NSEQ * BATCH * CMODEL;    // (B,N,N)

    const size_t NBC = (size_t)BATCH * NSEQ * CMODEL;         // 4,194,304
    const size_t WSZ = (size_t)CMODEL * CMODEL;               // 262,144
    unsigned short* q_ws  = (unsigned short*)d_ws;
    unsigned short* k_ws  = q_ws + NBC;
    unsigned short* v_ws  = k_ws + NBC;
    unsigned short* ctxbf = v_ws + NBC;
    unsigned short* qbf   = ctxbf + NBC;                      // converted inputs
    unsigned short* kbf   = qbf + NBC;
    unsigned short* vbf   = kbf + NBC;
    unsigned short* wqbf  = vbf + NBC;
    unsigned short* wkbf  = wqbf + WSZ;
    unsigned short* wvbf  = wkbf + WSZ;
    unsigned short* wobf  = wvbf + WSZ;
    int*   row_cnt  = (int*)(wobf + WSZ);                     // 8192 ints
    float* vm       = (float*)(row_cnt + BATCH * NSEQ);       // 4096 floats (contiguous)
    int*   row_list = (int*)(vm + BATCH * CMODEL);            // 8192*CAP ints

    convert_all<<<6704, 256, 0, stream>>>(query, key_t, value, Wq, Wk, Wv, Wo,
                                          qbf, kbf, vbf, wqbf, wkbf, wvbf, wobf,
                                          (unsigned int*)row_cnt);

    topk_scatter<<<2048, 256, 0, stream>>>(srcp, tgtp, row_cnt, row_list);

    gemm_proj<<<dim3(64, 4, 3), 256, 0, stream>>>(qbf, kbf, vbf,
                                                  wqbf, wkbf, wvbf,
                                                  bq, bk, bv,
                                                  q_ws, k_ws, v_ws);

    v_mean_k<<<dim3(BATCH, 16), 512, 0, stream>>>(v_ws, vm);

    sparse_attn<<<dim3(NSEQ, BATCH), 256, 0, stream>>>(q_ws, k_ws, v_ws, row_cnt,
                                                       row_list, vm, ctxbf, attn_out);

    gemm_out<<<dim3(64, 4), 256, 0, stream>>>(ctxbf, wobf, bo, out);
}